// Round 2
// baseline (3293.652 us; speedup 1.0000x reference)
//
#include <hip/hip_runtime.h>
#include <stdint.h>

#define BB 8
#define SS 4096
#define EE 512
#define PP 64
#define LL 4
#define FF 2048
#define HH 256
#define BS (BB*SS)

typedef unsigned short u16;
typedef __attribute__((ext_vector_type(8))) __bf16 bf16x8;
typedef __attribute__((ext_vector_type(4))) float f32x4;

__device__ __forceinline__ float b2f(u16 u) {
  union { float f; uint32_t u; } v; v.u = ((uint32_t)u) << 16; return v.f;
}
__device__ __forceinline__ u16 f2b(float f) {
  union { float f; uint32_t u; } v; v.f = f;
  uint32_t u = v.u;
  return (u16)((u + 0x7fffu + ((u >> 16) & 1u)) >> 16);
}
__device__ __forceinline__ float gelu_f(float x) {
  const float c = 0.7978845608028654f;
  float t = tanhf(c * (x + 0.044715f * x * x * x));
  return 0.5f * x * (1.0f + t);
}

// ---------------------------------------------------------------- zero
__global__ __launch_bounds__(256) void zero_kernel(float* __restrict__ p, int n) {
  int i = blockIdx.x * 256 + threadIdx.x;
  if (i < n) p[i] = 0.f;
}

// ---------------------------------------------------------------- embed (h fp32 only)
__global__ __launch_bounds__(128) void embed_kernel(const int* __restrict__ x,
                                                    const float* __restrict__ emb,
                                                    const float* __restrict__ pos,
                                                    float* __restrict__ hf) {
  int tok = blockIdx.x;
  int t = threadIdx.x;
  int s = tok & (SS - 1);
  int id = x[tok];
  int e = t * 4;
  float4 v = *(const float4*)(emb + (long)id * EE + e);
  float4 p = *(const float4*)(pos + (long)s * EE + e);
  v.x += p.x; v.y += p.y; v.z += p.z; v.w += p.w;
  *(float4*)(hf + (long)tok * EE + e) = v;
}

// ---------------------------------------------------------------- weight transpose fp32 -> bf16
__global__ __launch_bounds__(256) void transpose_kernel(const float* __restrict__ src,
                                                        u16* __restrict__ dst,
                                                        int R, int C,
                                                        long srcLS, long dstLS, int colOff) {
  __shared__ float tile[32][33];
  int l = blockIdx.z;
  src += (long)l * srcLS;
  dst += (long)l * dstLS;
  int c0 = blockIdx.x * 32, r0 = blockIdx.y * 32;
  int tx = threadIdx.x & 31, ty = threadIdx.x >> 5;
#pragma unroll
  for (int i = 0; i < 32; i += 8)
    tile[ty + i][tx] = src[(long)(r0 + ty + i) * C + c0 + tx];
  __syncthreads();
#pragma unroll
  for (int i = 0; i < 32; i += 8)
    dst[(long)(colOff + c0 + ty + i) * R + r0 + tx] = f2b(tile[tx][ty + i]);
}

// ---------------------------------------------------------------- generic NT GEMM (C = A * B^T)
// A: M x K (lda), B: N x K (ldb), tile 128x128, BK=64, 4 waves.
// EPI: 0 = g=elu(acc) -> bf16 ; 1 = bf16 ; 2 = a=(kwo+G*vwo+acc)/den -> f32
//      4 = gelu(acc+bias) -> bf16 ; 5 = hf += (residual): hf = acc+bias+hf
struct GemmP {
  const u16* A; const u16* B; const float* Af;
  int M, N, K, lda, ldb, ldc, rowOff;
  long sAz, sBz, sCz;
  float* Cf; u16* Cb;
  const float* bias;
  const float* den; const float* G;
  const float* kwo; const float* vwo;
  float* hf;
};

template<int EPI, int AF32>
__global__ __launch_bounds__(256) void gemm_nt(GemmP p) {
  __shared__ u16 As[128 * 64];
  __shared__ u16 Bs[128 * 64];
  const int z = blockIdx.z;
  const u16* Ap = p.A + (long)z * p.sAz;
  const u16* Bp = p.B + (long)z * p.sBz;
  const int m0 = blockIdx.y * 128, n0 = blockIdx.x * 128;
  const int t = threadIdx.x;
  const int l = t & 63, w = t >> 6;
  const int wr = w >> 1, wc = w & 1;
  const int r16 = l & 15, kg = l >> 4;

  f32x4 acc[4][4] = {};

  for (int k0 = 0; k0 < p.K; k0 += 64) {
#pragma unroll
    for (int i = 0; i < 4; ++i) {
      int cid = t + i * 256;
      int row = cid >> 3, c = cid & 7;
      uint4 va, vb;
      if constexpr (AF32) {
        const float* ap = p.Af + (long)(m0 + row) * p.lda + k0 + c * 8;
        float4 x0 = *(const float4*)(ap);
        float4 x1 = *(const float4*)(ap + 4);
        va.x = (uint32_t)f2b(x0.x) | ((uint32_t)f2b(x0.y) << 16);
        va.y = (uint32_t)f2b(x0.z) | ((uint32_t)f2b(x0.w) << 16);
        va.z = (uint32_t)f2b(x1.x) | ((uint32_t)f2b(x1.y) << 16);
        va.w = (uint32_t)f2b(x1.z) | ((uint32_t)f2b(x1.w) << 16);
      } else {
        va = *(const uint4*)(Ap + (long)(m0 + row) * p.lda + k0 + c * 8);
      }
      vb = *(const uint4*)(Bp + (long)(n0 + row) * p.ldb + k0 + c * 8);
      int sw = (c ^ (row & 7)) * 8;
      *(uint4*)(&As[row * 64 + sw]) = va;
      *(uint4*)(&Bs[row * 64 + sw]) = vb;
    }
    __syncthreads();
#pragma unroll
    for (int ks = 0; ks < 2; ++ks) {
      bf16x8 af[4], bfr[4];
#pragma unroll
      for (int mi = 0; mi < 4; ++mi) {
        int row = wr * 64 + mi * 16 + r16;
        int ch = (ks * 4 + kg) ^ (row & 7);
        af[mi] = *(const bf16x8*)(&As[row * 64 + ch * 8]);
      }
#pragma unroll
      for (int ni = 0; ni < 4; ++ni) {
        int row = wc * 64 + ni * 16 + r16;
        int ch = (ks * 4 + kg) ^ (row & 7);
        bfr[ni] = *(const bf16x8*)(&Bs[row * 64 + ch * 8]);
      }
#pragma unroll
      for (int mi = 0; mi < 4; ++mi)
#pragma unroll
        for (int ni = 0; ni < 4; ++ni)
          acc[mi][ni] = __builtin_amdgcn_mfma_f32_16x16x32_bf16(af[mi], bfr[ni], acc[mi][ni], 0, 0, 0);
    }
    __syncthreads();
  }

#pragma unroll
  for (int mi = 0; mi < 4; ++mi) {
#pragma unroll
    for (int ni = 0; ni < 4; ++ni) {
#pragma unroll
      for (int j = 0; j < 4; ++j) {
        int row = m0 + wr * 64 + mi * 16 + kg * 4 + j;
        int col = n0 + wc * 64 + ni * 16 + r16;
        float v = acc[mi][ni][j];
        long idx = (long)row * p.ldc + col;
        if constexpr (EPI == 0) {            // g = elu(acc)
          (p.Cb + (long)z * p.sCz)[idx] = f2b(v > 0.f ? v : expf(v) - 1.f);
        } else if constexpr (EPI == 1) {     // plain bf16
          (p.Cb + (long)z * p.sCz)[idx] = f2b(v);
        } else if constexpr (EPI == 2) {     // a = (kwo + G*vwo + xi*Wo)/den
          long grow = p.rowOff + row;
          int b = (int)(grow >> 12);
          float a = (p.kwo[(long)b * EE + col] + p.G[grow] * p.vwo[(long)b * EE + col] + v) / p.den[grow];
          p.Cf[idx] = a;
        } else if constexpr (EPI == 4) {     // gelu(acc + bias)
          p.Cb[idx] = f2b(gelu_f(v + p.bias[col]));
        } else {                             // residual: hf = acc + b2 + hf
          p.hf[idx] = v + p.bias[col] + p.hf[idx];
        }
      }
    }
  }
}

// ---------------------------------------------------------------- w[b][f][p] = sum_s g_k[b][s][p] * v[b][s][f]
__global__ __launch_bounds__(256) void kv_kernel(const u16* __restrict__ phi,
                                                 const u16* __restrict__ v,
                                                 float* __restrict__ kvf) {
  __shared__ u16 ph[16 * 64];
  __shared__ u16 vs[16 * 64];
  int f0 = blockIdx.x * 64;
  int b = blockIdx.z;
  int s0 = blockIdx.y * (SS / 16);
  int t = threadIdx.x;
  int fl = t & 63;
  int pb = (t >> 6) * 16;
  float acc[16] = {};
  int r = t >> 4, col = (t & 15) * 4;
  for (int c = 0; c < SS / 16; c += 16) {
    long s = (long)b * SS + s0 + c + r;
    *(uint2*)(ph + r * 64 + col) = *(const uint2*)(phi + s * 128 + 64 + col);
    *(uint2*)(vs + r * 64 + col) = *(const uint2*)(v + s * EE + f0 + col);
    __syncthreads();
#pragma unroll
    for (int ss = 0; ss < 16; ++ss) {
      float vv = b2f(vs[ss * 64 + fl]);
#pragma unroll
      for (int i = 0; i < 16; ++i)
        acc[i] += b2f(ph[ss * 64 + pb + i]) * vv;
    }
    __syncthreads();
  }
#pragma unroll
  for (int i = 0; i < 16; ++i)
    atomicAdd(&kvf[((long)b * EE + f0 + fl) * PP + pb + i], acc[i]);
}

// ---------------------------------------------------------------- zg[b][p] = sum_s g_k
__global__ __launch_bounds__(256) void zg_kernel(const u16* __restrict__ phi, float* __restrict__ zg) {
  int p = blockIdx.x, b = blockIdx.y, t = threadIdx.x;
  float a = 0.f;
  for (int s = t; s < SS; s += 256)
    a += b2f(phi[((long)b * SS + s) * 128 + 64 + p]);
  __shared__ float red[256];
  red[t] = a; __syncthreads();
  for (int o = 128; o > 0; o >>= 1) { if (t < o) red[t] += red[t + o]; __syncthreads(); }
  if (t == 0) zg[b * PP + p] = red[0];
}

// ---------------------------------------------------------------- hbar[b][f] += sum_s hf (partial, atomic)
__global__ __launch_bounds__(256) void hbar_kernel(const float* __restrict__ hf, float* __restrict__ hb) {
  int f = blockIdx.y * 256 + threadIdx.x;
  int b = blockIdx.x;
  long s0 = blockIdx.z * 256;
  const float* p = hf + ((long)b * SS + s0) * EE + f;
  float a = 0.f;
  for (int s = 0; s < 256; ++s) a += p[(long)s * EE];
  atomicAdd(&hb[b * EE + f], a);
}

// ---------------------------------------------------------------- out[b][j] = sum_f in[b][f] * W[f][j]  (fp32, W ld=EE)
__global__ __launch_bounds__(256) void smallmm_kernel(const float* __restrict__ in,
                                                      const float* __restrict__ W,
                                                      float* __restrict__ out) {
  int j = blockIdx.x * 256 + threadIdx.x;
  int b = blockIdx.y;
  const float* ib = in + b * EE;
  float s = 0.f;
  for (int f = 0; f < EE; ++f) s += ib[f] * W[(long)f * EE + j];
  out[b * EE + j] = s;
}

// ---------------------------------------------------------------- kbar = 64*vbar + sum_p w
__global__ __launch_bounds__(256) void kbar_kernel(const float* __restrict__ kvf,
                                                   const float* __restrict__ vbar,
                                                   float* __restrict__ kb) {
  int i = blockIdx.x * 256 + threadIdx.x;  // b*EE+f
  const float* wp = kvf + (long)i * PP;
  float s = 0.f;
#pragma unroll
  for (int p = 0; p < PP; ++p) s += wp[p];
  kb[i] = 64.f * vbar[i] + s;
}

// ---------------------------------------------------------------- fp32 -> bf16
__global__ __launch_bounds__(256) void cvt_kernel(const float* __restrict__ in, u16* __restrict__ out, int n) {
  int i = blockIdx.x * 256 + threadIdx.x;
  if (i < n) out[i] = f2b(in[i]);
}

// ---------------------------------------------------------------- den[s], G[s] from g_q, zg
__global__ __launch_bounds__(256) void den_kernel(const u16* __restrict__ phi,
                                                  const float* __restrict__ zg,
                                                  float* __restrict__ den,
                                                  float* __restrict__ G) {
  long row = (long)blockIdx.x * 256 + threadIdx.x;
  int b = (int)(row >> 12);
  const u16* pr = phi + row * 128;
  const float* zb = zg + b * PP;
  float Gs = 0.f, dot = 0.f, Z = 0.f;
#pragma unroll
  for (int p = 0; p < PP; ++p) {
    float gq = b2f(pr[p]);
    float zz = zb[p];
    Gs += gq; dot += gq * zz; Z += zz;
  }
  den[row] = 64.f * 4096.f + 4096.f * Gs + Z + dot + 1e-6f;
  G[row] = Gs;
}

// ---------------------------------------------------------------- layernorm (wave per row), f32 in -> bf16 out
__global__ __launch_bounds__(256) void ln_kernel(const float* __restrict__ a,
                                                 const float* __restrict__ g,
                                                 const float* __restrict__ beta,
                                                 u16* __restrict__ out) {
  int w = threadIdx.x >> 6, l = threadIdx.x & 63;
  long row = (long)blockIdx.x * 4 + w;
  int e = l * 8;
  const float* x = a + row * EE + e;
  float4 v0 = *(const float4*)(x);
  float4 v1 = *(const float4*)(x + 4);
  float vals[8] = {v0.x, v0.y, v0.z, v0.w, v1.x, v1.y, v1.z, v1.w};
  float sum = 0.f, sq = 0.f;
#pragma unroll
  for (int j = 0; j < 8; ++j) { sum += vals[j]; sq += vals[j] * vals[j]; }
#pragma unroll
  for (int o = 1; o < 64; o <<= 1) {
    sum += __shfl_xor(sum, o, 64);
    sq  += __shfl_xor(sq,  o, 64);
  }
  float mu = sum * (1.f / EE);
  float var = sq * (1.f / EE) - mu * mu;
  float rs = rsqrtf(var + 1e-5f);
  u16 ov[8];
#pragma unroll
  for (int j = 0; j < 8; ++j)
    ov[j] = f2b((vals[j] - mu) * rs * g[e + j] + beta[e + j]);
  *(ushort4*)(out + row * EE + e) = *(ushort4*)&ov[0];
  *(ushort4*)(out + row * EE + e + 4) = *(ushort4*)&ov[4];
}

// ---------------------------------------------------------------- head (fp32 exact)
__global__ __launch_bounds__(256) void head_kernel(const float* __restrict__ hf,
                                                   const float* __restrict__ Wh1,
                                                   const float* __restrict__ bh1,
                                                   const float* __restrict__ Wh2,
                                                   const float* __restrict__ bh2,
                                                   float* __restrict__ out) {
  int t = threadIdx.x;
  __shared__ float red[256];
  for (int b = 0; b < BB; ++b) {
    const float* pb = hf + (long)b * SS * EE;
    float a = bh1[t];
    for (int e = 0; e < EE; ++e) a += pb[e] * Wh1[(long)e * HH + t];
    a = fmaxf(a, 0.f);
    for (int c = 0; c < 2; ++c) {
      red[t] = a * Wh2[t * 2 + c];
      __syncthreads();
      for (int o = 128; o > 0; o >>= 1) { if (t < o) red[t] += red[t + o]; __syncthreads(); }
      if (t == 0) out[b * 2 + c] = red[0] + bh2[c];
      __syncthreads();
    }
  }
}

// ---------------------------------------------------------------- launch
extern "C" void kernel_launch(void* const* d_in, const int* in_sizes, int n_in,
                              void* d_out, int out_size, void* d_ws, size_t ws_size,
                              hipStream_t stream) {
  (void)in_sizes; (void)n_in; (void)out_size;
  const int*   x   = (const int*)d_in[0];
  const float* emb = (const float*)d_in[1];
  const float* pos = (const float*)d_in[2];
  const float* Wq  = (const float*)d_in[3];
  const float* Wk  = (const float*)d_in[4];
  const float* Wv  = (const float*)d_in[5];
  const float* Wo  = (const float*)d_in[6];
  const float* lng = (const float*)d_in[7];
  const float* lnb = (const float*)d_in[8];
  const float* W1  = (const float*)d_in[9];
  const float* b1  = (const float*)d_in[10];
  const float* W2  = (const float*)d_in[11];
  const float* b2  = (const float*)d_in[12];
  const float* Wh1 = (const float*)d_in[13];
  const float* bh1 = (const float*)d_in[14];
  const float* Wh2 = (const float*)d_in[15];
  const float* bh2 = (const float*)d_in[16];
  float* out = (float*)d_out;

  char* ws = (char*)d_ws;
  size_t off = 0;
  auto alloc = [&](size_t bytes) {
    char* p = ws + off;
    off = (off + bytes + 255) & ~(size_t)255;
    return p;
  };
  float* hf   = (float*)alloc((size_t)BS * EE * 4);          // 64 MB residual (fp32, persistent)
  u16*   phi  = (u16*)  alloc((size_t)BS * 128 * 2);         // g = elu(qk), bf16
  u16*   sbuf = (u16*)  alloc((size_t)BS * EE * 2);          // shared: v -> xi -> n (bf16)
  float* den  = (float*)alloc((size_t)BS * 4);
  float* Gbuf = (float*)alloc((size_t)BS * 4);
  float* kvf  = (float*)alloc((size_t)BB * EE * PP * 4 + (size_t)BB * EE * 4);  // w + hbar
  float* hbar = kvf + (size_t)BB * EE * PP;
  u16*   kvb  = (u16*)  alloc((size_t)BB * EE * PP * 2);
  float* zg   = (float*)alloc((size_t)BB * PP * 4);
  float* vbar = (float*)alloc((size_t)BB * EE * 4);
  float* kbar = (float*)alloc((size_t)BB * EE * 4);
  float* kwo  = (float*)alloc((size_t)BB * EE * 4);
  float* vwo  = (float*)alloc((size_t)BB * EE * 4);
  u16* wqkT = (u16*)alloc((size_t)LL * 128 * EE * 2);
  u16* wvT  = (u16*)alloc((size_t)LL * EE * EE * 2);
  u16* woT  = (u16*)alloc((size_t)LL * EE * EE * 2);
  u16* w1T  = (u16*)alloc((size_t)LL * FF * EE * 2);
  u16* w2T  = (u16*)alloc((size_t)LL * EE * FF * 2);

  // FFN region: af (fp32 LN input) + mbf (bf16 FFN mid), row-chunked to fit ws_size
  size_t rem = (ws_size > off) ? ws_size - off : 0;
  int CH;
  if ((size_t)BS * FF * 2 <= rem) CH = 1;                                  // af aliases mbf
  else if (((size_t)BS * EE * 4 + (size_t)BS * FF * 2) / 2 <= rem) CH = 2;
  else if (((size_t)BS * EE * 4 + (size_t)BS * FF * 2) / 4 <= rem) CH = 4;
  else if (((size_t)BS * EE * 4 + (size_t)BS * FF * 2) / 8 <= rem) CH = 8;
  else CH = 16;
  const int MC = BS / CH;
  char* regp = ws + off;
  float* af = (float*)regp;
  u16* mbf = (CH == 1) ? (u16*)regp : (u16*)(regp + (size_t)MC * EE * 4);

  embed_kernel<<<BS, 128, 0, stream>>>(x, emb, pos, hf);
  transpose_kernel<<<dim3(PP/32, EE/32, LL), 256, 0, stream>>>(Wq, wqkT, EE, PP, (long)EE*PP, (long)128*EE, 0);
  transpose_kernel<<<dim3(PP/32, EE/32, LL), 256, 0, stream>>>(Wk, wqkT, EE, PP, (long)EE*PP, (long)128*EE, 64);
  transpose_kernel<<<dim3(EE/32, EE/32, LL), 256, 0, stream>>>(Wv, wvT, EE, EE, (long)EE*EE, (long)EE*EE, 0);
  transpose_kernel<<<dim3(EE/32, EE/32, LL), 256, 0, stream>>>(Wo, woT, EE, EE, (long)EE*EE, (long)EE*EE, 0);
  transpose_kernel<<<dim3(FF/32, EE/32, LL), 256, 0, stream>>>(W1, w1T, EE, FF, (long)EE*FF, (long)FF*EE, 0);
  transpose_kernel<<<dim3(EE/32, FF/32, LL), 256, 0, stream>>>(W2, w2T, FF, EE, (long)FF*EE, (long)EE*FF, 0);

  for (int l = 0; l < LL; ++l) {
    zero_kernel<<<(BB*EE*PP + BB*EE + 255)/256, 256, 0, stream>>>(kvf, BB*EE*PP + BB*EE);
    hbar_kernel<<<dim3(BB, EE/256, 16), 256, 0, stream>>>(hf, hbar);
    smallmm_kernel<<<dim3(EE/256, BB), 256, 0, stream>>>(hbar, Wv + (size_t)l*EE*EE, vbar);
    {  // g = elu([h Wq | h Wk])
      GemmP p{};
      p.Af = hf; p.B = wqkT + (size_t)l * 128 * EE;
      p.M = BS; p.N = 128; p.K = EE;
      p.lda = EE; p.ldb = EE; p.ldc = 128; p.Cb = phi;
      gemm_nt<0, 1><<<dim3(1, BS/128, 1), 256, 0, stream>>>(p);
    }
    {  // v = h Wv (bf16)
      GemmP p{};
      p.Af = hf; p.B = wvT + (size_t)l * EE * EE;
      p.M = BS; p.N = EE; p.K = EE;
      p.lda = EE; p.ldb = EE; p.ldc = EE; p.Cb = sbuf;
      gemm_nt<1, 1><<<dim3(EE/128, BS/128, 1), 256, 0, stream>>>(p);
    }
    zg_kernel<<<dim3(PP, BB), 256, 0, stream>>>(phi, zg);
    kv_kernel<<<dim3(EE/64, 16, BB), 256, 0, stream>>>(phi, sbuf, kvf);
    cvt_kernel<<<(BB*EE*PP + 255)/256, 256, 0, stream>>>(kvf, kvb, BB*EE*PP);
    kbar_kernel<<<BB*EE/256, 256, 0, stream>>>(kvf, vbar, kbar);
    smallmm_kernel<<<dim3(EE/256, BB), 256, 0, stream>>>(kbar, Wo + (size_t)l*EE*EE, kwo);
    smallmm_kernel<<<dim3(EE/256, BB), 256, 0, stream>>>(vbar, Wo + (size_t)l*EE*EE, vwo);
    den_kernel<<<BS/256, 256, 0, stream>>>(phi, zg, den, Gbuf);
    {  // xi = g_q . w  (bf16)
      GemmP p{};
      p.A = phi; p.B = kvb;
      p.M = SS; p.N = EE; p.K = PP;
      p.lda = 128; p.ldb = PP; p.ldc = EE;
      p.sAz = (long)SS * 128; p.sBz = (long)EE * PP; p.sCz = (long)SS * EE;
      p.Cb = sbuf;
      gemm_nt<1, 0><<<dim3(EE/128, SS/128, BB), 256, 0, stream>>>(p);
    }
    for (int ch = 0; ch < CH; ++ch) {
      int R0 = ch * MC;
      {  // a = (kwo + G*vwo + xi Wo)/den  (fp32)
        GemmP p{};
        p.A = sbuf + (size_t)R0 * EE; p.B = woT + (size_t)l * EE * EE;
        p.M = MC; p.N = EE; p.K = EE;
        p.lda = EE; p.ldb = EE; p.ldc = EE; p.rowOff = R0;
        p.Cf = af; p.den = den; p.G = Gbuf; p.kwo = kwo; p.vwo = vwo;
        gemm_nt<2, 0><<<dim3(EE/128, MC/128, 1), 256, 0, stream>>>(p);
      }
      ln_kernel<<<MC/4, 256, 0, stream>>>(af, lng + (size_t)l*EE, lnb + (size_t)l*EE, sbuf + (size_t)R0 * EE);
      {  // m = gelu(n W1 + b1)
        GemmP p{};
        p.A = sbuf + (size_t)R0 * EE; p.B = w1T + (size_t)l * FF * EE;
        p.M = MC; p.N = FF; p.K = EE;
        p.lda = EE; p.ldb = EE; p.ldc = FF; p.Cb = mbf; p.bias = b1 + (size_t)l * FF;
        gemm_nt<4, 0><<<dim3(FF/128, MC/128, 1), 256, 0, stream>>>(p);
      }
      {  // h += m W2 + b2
        GemmP p{};
        p.A = mbf; p.B = w2T + (size_t)l * EE * FF;
        p.M = MC; p.N = EE; p.K = FF;
        p.lda = FF; p.ldb = FF; p.ldc = EE;
        p.hf = hf + (size_t)R0 * EE; p.bias = b2 + (size_t)l * EE;
        gemm_nt<5, 0><<<dim3(EE/128, MC/128, 1), 256, 0, stream>>>(p);
      }
    }
  }
  head_kernel<<<1, 256, 0, stream>>>(hf, Wh1, bh1, Wh2, bh2, out);
}

// Round 3
// 2775.263 us; speedup vs baseline: 1.1868x; 1.1868x over previous
//
#include <hip/hip_runtime.h>
#include <stdint.h>

#define BB 8
#define SS 4096
#define EE 512
#define PP 64
#define LL 4
#define FF 2048
#define HH 256
#define BS (BB*SS)
#define NKV 16   // kv split-K factor

typedef unsigned short u16;
typedef __attribute__((ext_vector_type(8))) __bf16 bf16x8;
typedef __attribute__((ext_vector_type(4))) float f32x4;

__device__ __forceinline__ float b2f(u16 u) {
  union { float f; uint32_t u; } v; v.u = ((uint32_t)u) << 16; return v.f;
}
__device__ __forceinline__ u16 f2b(float f) {
  union { float f; uint32_t u; } v; v.f = f;
  uint32_t u = v.u;
  return (u16)((u + 0x7fffu + ((u >> 16) & 1u)) >> 16);
}
__device__ __forceinline__ float gelu_f(float x) {
  const float c = 0.7978845608028654f;
  float t = tanhf(c * (x + 0.044715f * x * x * x));
  return 0.5f * x * (1.0f + t);
}

// ---------------------------------------------------------------- zero
__global__ __launch_bounds__(256) void zero_kernel(float* __restrict__ p, int n) {
  int i = blockIdx.x * 256 + threadIdx.x;
  if (i < n) p[i] = 0.f;
}

// ---------------------------------------------------------------- embed (hf fp32 + hb bf16)
__global__ __launch_bounds__(128) void embed_kernel(const int* __restrict__ x,
                                                    const float* __restrict__ emb,
                                                    const float* __restrict__ pos,
                                                    float* __restrict__ hf,
                                                    u16* __restrict__ hb) {
  int tok = blockIdx.x;
  int t = threadIdx.x;
  int s = tok & (SS - 1);
  int id = x[tok];
  int e = t * 4;
  float4 v = *(const float4*)(emb + (long)id * EE + e);
  float4 p = *(const float4*)(pos + (long)s * EE + e);
  v.x += p.x; v.y += p.y; v.z += p.z; v.w += p.w;
  *(float4*)(hf + (long)tok * EE + e) = v;
  ushort4 u;
  u.x = f2b(v.x); u.y = f2b(v.y); u.z = f2b(v.z); u.w = f2b(v.w);
  *(ushort4*)(hb + (long)tok * EE + e) = u;
}

// ---------------------------------------------------------------- weight transpose fp32 -> bf16
__global__ __launch_bounds__(256) void transpose_kernel(const float* __restrict__ src,
                                                        u16* __restrict__ dst,
                                                        int R, int C,
                                                        long srcLS, long dstLS, int colOff) {
  __shared__ float tile[32][33];
  int l = blockIdx.z;
  src += (long)l * srcLS;
  dst += (long)l * dstLS;
  int c0 = blockIdx.x * 32, r0 = blockIdx.y * 32;
  int tx = threadIdx.x & 31, ty = threadIdx.x >> 5;
#pragma unroll
  for (int i = 0; i < 32; i += 8)
    tile[ty + i][tx] = src[(long)(r0 + ty + i) * C + c0 + tx];
  __syncthreads();
#pragma unroll
  for (int i = 0; i < 32; i += 8)
    dst[(long)(colOff + c0 + ty + i) * R + r0 + tx] = f2b(tile[tx][ty + i]);
}

// ---------------------------------------------------------------- generic NT GEMM (C = A * B^T), bf16 in, f32 acc
// A: M x K (lda), B: N x K (ldb), tile 128x128, BK=64, 4 waves.
// EPI: 0 = elu(acc)->bf16 ; 1 = bf16 ; 2 = (kwo+G*vwo+acc)/den -> f32
//      4 = gelu(acc+bias)->bf16 ; 5 = residual: hf = acc+bias+hf, hb = bf16(hf)
struct GemmP {
  const u16* A; const u16* B;
  int M, N, K, lda, ldb, ldc, rowOff;
  long sAz, sBz, sCz;
  float* Cf; u16* Cb;
  const float* bias;
  const float* den; const float* G;
  const float* kwo; const float* vwo;
  float* hf;
};

template<int EPI>
__global__ __launch_bounds__(256) void gemm_nt(GemmP p) {
  __shared__ u16 As[128 * 64];
  __shared__ u16 Bs[128 * 64];
  const int z = blockIdx.z;
  const u16* Ap = p.A + (long)z * p.sAz;
  const u16* Bp = p.B + (long)z * p.sBz;
  const int m0 = blockIdx.y * 128, n0 = blockIdx.x * 128;
  const int t = threadIdx.x;
  const int l = t & 63, w = t >> 6;
  const int wr = w >> 1, wc = w & 1;
  const int r16 = l & 15, kg = l >> 4;

  f32x4 acc[4][4] = {};

  for (int k0 = 0; k0 < p.K; k0 += 64) {
#pragma unroll
    for (int i = 0; i < 4; ++i) {
      int cid = t + i * 256;
      int row = cid >> 3, c = cid & 7;
      uint4 va = *(const uint4*)(Ap + (long)(m0 + row) * p.lda + k0 + c * 8);
      uint4 vb = *(const uint4*)(Bp + (long)(n0 + row) * p.ldb + k0 + c * 8);
      int sw = (c ^ (row & 7)) * 8;
      *(uint4*)(&As[row * 64 + sw]) = va;
      *(uint4*)(&Bs[row * 64 + sw]) = vb;
    }
    __syncthreads();
#pragma unroll
    for (int ks = 0; ks < 2; ++ks) {
      bf16x8 af[4], bfr[4];
#pragma unroll
      for (int mi = 0; mi < 4; ++mi) {
        int row = wr * 64 + mi * 16 + r16;
        int ch = (ks * 4 + kg) ^ (row & 7);
        af[mi] = *(const bf16x8*)(&As[row * 64 + ch * 8]);
      }
#pragma unroll
      for (int ni = 0; ni < 4; ++ni) {
        int row = wc * 64 + ni * 16 + r16;
        int ch = (ks * 4 + kg) ^ (row & 7);
        bfr[ni] = *(const bf16x8*)(&Bs[row * 64 + ch * 8]);
      }
#pragma unroll
      for (int mi = 0; mi < 4; ++mi)
#pragma unroll
        for (int ni = 0; ni < 4; ++ni)
          acc[mi][ni] = __builtin_amdgcn_mfma_f32_16x16x32_bf16(af[mi], bfr[ni], acc[mi][ni], 0, 0, 0);
    }
    __syncthreads();
  }

#pragma unroll
  for (int mi = 0; mi < 4; ++mi) {
#pragma unroll
    for (int ni = 0; ni < 4; ++ni) {
#pragma unroll
      for (int j = 0; j < 4; ++j) {
        int row = m0 + wr * 64 + mi * 16 + kg * 4 + j;
        int col = n0 + wc * 64 + ni * 16 + r16;
        float v = acc[mi][ni][j];
        long idx = (long)row * p.ldc + col;
        if constexpr (EPI == 0) {            // g = elu(acc)
          (p.Cb + (long)z * p.sCz)[idx] = f2b(v > 0.f ? v : expf(v) - 1.f);
        } else if constexpr (EPI == 1) {     // plain bf16
          (p.Cb + (long)z * p.sCz)[idx] = f2b(v);
        } else if constexpr (EPI == 2) {     // a = (kwo + G*vwo + xi*Wo)/den
          long grow = p.rowOff + row;
          int b = (int)(grow >> 12);
          float a = (p.kwo[(long)b * EE + col] + p.G[grow] * p.vwo[(long)b * EE + col] + v) / p.den[grow];
          p.Cf[idx] = a;
        } else if constexpr (EPI == 4) {     // gelu(acc + bias)
          p.Cb[idx] = f2b(gelu_f(v + p.bias[col]));
        } else {                             // residual
          float r = v + p.bias[col] + p.hf[idx];
          p.hf[idx] = r;
          p.Cb[idx] = f2b(r);
        }
      }
    }
  }
}

// ---------------------------------------------------------------- kv via MFMA, split-K partials
// kvpart[kidx][b][f][p] = sum_{s in chunk} phi_k[b][s][p] * v[b][s][f]
// grid (EE/128, NKV, BB), 256 thr. M=64 (p), N=128 (f tile), K=256 s per block.
__global__ __launch_bounds__(256) void kv_mfma(const u16* __restrict__ phi,
                                               const u16* __restrict__ v,
                                               float* __restrict__ kvpart) {
  __shared__ u16 phT[64 * 72];    // [p][s] stride 72
  __shared__ u16 vTs[128 * 72];   // [f][s] stride 72
  const int f0 = blockIdx.x * 128;
  const int kidx = blockIdx.y;
  const int b = blockIdx.z;
  const int t = threadIdx.x;
  const int l = t & 63, w = t >> 6;
  const int r16 = l & 15, kg = l >> 4;

  f32x4 acc[4][2] = {};

  for (int kc = 0; kc < 4; ++kc) {
    const long srow = (long)b * SS + kidx * 256 + kc * 64;
    // stage phi_k chunk transposed: phT[p][s_local]
#pragma unroll
    for (int pass = 0; pass < 2; ++pass) {
      int pp = t & 63;
      int sb = ((t >> 6) << 3) + pass * 32;
      u16 tmp[8];
#pragma unroll
      for (int j = 0; j < 8; ++j)
        tmp[j] = phi[(srow + sb + j) * 128 + 64 + pp];
      uint4 pk;
      pk.x = (uint32_t)tmp[0] | ((uint32_t)tmp[1] << 16);
      pk.y = (uint32_t)tmp[2] | ((uint32_t)tmp[3] << 16);
      pk.z = (uint32_t)tmp[4] | ((uint32_t)tmp[5] << 16);
      pk.w = (uint32_t)tmp[6] | ((uint32_t)tmp[7] << 16);
      *(uint4*)(&phT[pp * 72 + sb]) = pk;
    }
    // stage v chunk transposed: vTs[f][s_local]
#pragma unroll
    for (int pass = 0; pass < 4; ++pass) {
      int ff = t & 127;
      int sb = ((t >> 7) << 3) + pass * 16;
      u16 tmp[8];
#pragma unroll
      for (int j = 0; j < 8; ++j)
        tmp[j] = v[(srow + sb + j) * EE + f0 + ff];
      uint4 pk;
      pk.x = (uint32_t)tmp[0] | ((uint32_t)tmp[1] << 16);
      pk.y = (uint32_t)tmp[2] | ((uint32_t)tmp[3] << 16);
      pk.z = (uint32_t)tmp[4] | ((uint32_t)tmp[5] << 16);
      pk.w = (uint32_t)tmp[6] | ((uint32_t)tmp[7] << 16);
      *(uint4*)(&vTs[ff * 72 + sb]) = pk;
    }
    __syncthreads();
#pragma unroll
    for (int ks = 0; ks < 2; ++ks) {
      int sloc = ks * 32 + kg * 8;
      bf16x8 af[4], bfr[2];
#pragma unroll
      for (int mi = 0; mi < 4; ++mi)
        af[mi] = *(const bf16x8*)(&phT[(mi * 16 + r16) * 72 + sloc]);
#pragma unroll
      for (int ni = 0; ni < 2; ++ni)
        bfr[ni] = *(const bf16x8*)(&vTs[(w * 32 + ni * 16 + r16) * 72 + sloc]);
#pragma unroll
      for (int mi = 0; mi < 4; ++mi)
#pragma unroll
        for (int ni = 0; ni < 2; ++ni)
          acc[mi][ni] = __builtin_amdgcn_mfma_f32_16x16x32_bf16(af[mi], bfr[ni], acc[mi][ni], 0, 0, 0);
    }
    __syncthreads();
  }

  float* outp = kvpart + ((long)kidx * BB + b) * EE * PP;
#pragma unroll
  for (int mi = 0; mi < 4; ++mi) {
#pragma unroll
    for (int ni = 0; ni < 2; ++ni) {
#pragma unroll
      for (int j = 0; j < 4; ++j) {
        int pidx = mi * 16 + kg * 4 + j;
        int fidx = f0 + w * 32 + ni * 16 + r16;
        outp[(long)fidx * PP + pidx] = acc[mi][ni][j];
      }
    }
  }
}

// ---------------------------------------------------------------- kv reduce: sum NKV partials -> kvf (f32) + kvb (bf16)
__global__ __launch_bounds__(256) void kvreduce(const float* __restrict__ kvpart,
                                                float* __restrict__ kvf,
                                                u16* __restrict__ kvb) {
  long i = (long)blockIdx.x * 256 + threadIdx.x;
  const long SKV = (long)BB * EE * PP;
  float s = 0.f;
#pragma unroll
  for (int k = 0; k < NKV; ++k) s += kvpart[k * SKV + i];
  kvf[i] = s;
  kvb[i] = f2b(s);
}

// ---------------------------------------------------------------- zg[b][p] = sum_s g_k
__global__ __launch_bounds__(256) void zg_kernel(const u16* __restrict__ phi, float* __restrict__ zg) {
  int p = blockIdx.x, b = blockIdx.y, t = threadIdx.x;
  float a = 0.f;
  for (int s = t; s < SS; s += 256)
    a += b2f(phi[((long)b * SS + s) * 128 + 64 + p]);
  __shared__ float red[256];
  red[t] = a; __syncthreads();
  for (int o = 128; o > 0; o >>= 1) { if (t < o) red[t] += red[t + o]; __syncthreads(); }
  if (t == 0) zg[b * PP + p] = red[0];
}

// ---------------------------------------------------------------- hbar[b][f] += partial sums of hf
__global__ __launch_bounds__(256) void hbar_kernel(const float* __restrict__ hf, float* __restrict__ hb) {
  int f = blockIdx.y * 256 + threadIdx.x;
  int b = blockIdx.x;
  long s0 = blockIdx.z * 256;
  const float* p = hf + ((long)b * SS + s0) * EE + f;
  float a = 0.f;
  for (int s = 0; s < 256; ++s) a += p[(long)s * EE];
  atomicAdd(&hb[b * EE + f], a);
}

// ---------------------------------------------------------------- out[b][j] = sum_f in[b][f] * W[f][j]
__global__ __launch_bounds__(256) void smallmm_kernel(const float* __restrict__ in,
                                                      const float* __restrict__ W,
                                                      float* __restrict__ out) {
  int j = blockIdx.x * 256 + threadIdx.x;
  int b = blockIdx.y;
  const float* ib = in + b * EE;
  float s = 0.f;
  for (int f = 0; f < EE; ++f) s += ib[f] * W[(long)f * EE + j];
  out[b * EE + j] = s;
}

// ---------------------------------------------------------------- kbar = 64*vbar + sum_p w
__global__ __launch_bounds__(256) void kbar_kernel(const float* __restrict__ kvf,
                                                   const float* __restrict__ vbar,
                                                   float* __restrict__ kb) {
  int i = blockIdx.x * 256 + threadIdx.x;
  const float* wp = kvf + (long)i * PP;
  float s = 0.f;
#pragma unroll
  for (int p = 0; p < PP; ++p) s += wp[p];
  kb[i] = 64.f * vbar[i] + s;
}

// ---------------------------------------------------------------- den[s], G[s]
__global__ __launch_bounds__(256) void den_kernel(const u16* __restrict__ phi,
                                                  const float* __restrict__ zg,
                                                  float* __restrict__ den,
                                                  float* __restrict__ G) {
  long row = (long)blockIdx.x * 256 + threadIdx.x;
  int b = (int)(row >> 12);
  const u16* pr = phi + row * 128;
  const float* zb = zg + b * PP;
  float Gs = 0.f, dot = 0.f, Z = 0.f;
#pragma unroll
  for (int c = 0; c < 8; ++c) {
    uint4 q = *(const uint4*)(pr + c * 8);
    u16 uu[8] = {(u16)(q.x & 0xffff), (u16)(q.x >> 16), (u16)(q.y & 0xffff), (u16)(q.y >> 16),
                 (u16)(q.z & 0xffff), (u16)(q.z >> 16), (u16)(q.w & 0xffff), (u16)(q.w >> 16)};
#pragma unroll
    for (int i = 0; i < 8; ++i) {
      float gq = b2f(uu[i]);
      float zz = zb[c * 8 + i];
      Gs += gq; dot += gq * zz; Z += zz;
    }
  }
  den[row] = 64.f * 4096.f + 4096.f * Gs + Z + dot + 1e-6f;
  G[row] = Gs;
}

// ---------------------------------------------------------------- layernorm (wave per row), f32 in -> bf16 out
__global__ __launch_bounds__(256) void ln_kernel(const float* __restrict__ a,
                                                 const float* __restrict__ g,
                                                 const float* __restrict__ beta,
                                                 u16* __restrict__ out) {
  int w = threadIdx.x >> 6, l = threadIdx.x & 63;
  long row = (long)blockIdx.x * 4 + w;
  int e = l * 8;
  const float* x = a + row * EE + e;
  float4 v0 = *(const float4*)(x);
  float4 v1 = *(const float4*)(x + 4);
  float vals[8] = {v0.x, v0.y, v0.z, v0.w, v1.x, v1.y, v1.z, v1.w};
  float sum = 0.f, sq = 0.f;
#pragma unroll
  for (int j = 0; j < 8; ++j) { sum += vals[j]; sq += vals[j] * vals[j]; }
#pragma unroll
  for (int o = 1; o < 64; o <<= 1) {
    sum += __shfl_xor(sum, o, 64);
    sq  += __shfl_xor(sq,  o, 64);
  }
  float mu = sum * (1.f / EE);
  float var = sq * (1.f / EE) - mu * mu;
  float rs = rsqrtf(var + 1e-5f);
  u16 ov[8];
#pragma unroll
  for (int j = 0; j < 8; ++j)
    ov[j] = f2b((vals[j] - mu) * rs * g[e + j] + beta[e + j]);
  *(ushort4*)(out + row * EE + e) = *(ushort4*)&ov[0];
  *(ushort4*)(out + row * EE + e + 4) = *(ushort4*)&ov[4];
}

// ---------------------------------------------------------------- last layer, s=0 rows only (fp32 exact)
__global__ __launch_bounds__(256) void lastrow_kernel(const u16* __restrict__ phi,
                                                      const float* __restrict__ kvf,
                                                      const float* __restrict__ kwo,
                                                      const float* __restrict__ vwo,
                                                      const float* __restrict__ G,
                                                      const float* __restrict__ den,
                                                      const float* __restrict__ hf,
                                                      const float* __restrict__ Wo,
                                                      const float* __restrict__ W1,
                                                      const float* __restrict__ b1,
                                                      const float* __restrict__ W2,
                                                      const float* __restrict__ b2,
                                                      const float* __restrict__ lng,
                                                      const float* __restrict__ lnb,
                                                      float* __restrict__ hfin) {
  __shared__ float xi[EE];
  __shared__ float av[EE];
  __shared__ float nn[EE];
  __shared__ float mm[FF];
  __shared__ float red[256];
  int b = blockIdx.x;
  int t = threadIdx.x;
  long r = (long)b * SS;   // s = 0 row
  // xi[f] = g_q . kv[:,f]
  for (int f = t; f < EE; f += 256) {
    float s = 0.f;
    const float* kp = kvf + ((long)b * EE + f) * PP;
#pragma unroll
    for (int p = 0; p < PP; ++p) s += b2f(phi[r * 128 + p]) * kp[p];
    xi[f] = s;
  }
  __syncthreads();
  float Gr = G[r], dr = den[r];
  for (int e = t; e < EE; e += 256) {
    float s = 0.f;
    for (int f = 0; f < EE; ++f) s += xi[f] * Wo[(long)f * EE + e];
    av[e] = (kwo[b * EE + e] + Gr * vwo[b * EE + e] + s) / dr;
  }
  __syncthreads();
  float ps = 0.f, pq = 0.f;
  for (int e = t; e < EE; e += 256) { float v = av[e]; ps += v; pq += v * v; }
  red[t] = ps; __syncthreads();
  for (int o = 128; o > 0; o >>= 1) { if (t < o) red[t] += red[t + o]; __syncthreads(); }
  float mu = red[0] * (1.f / EE);
  __syncthreads();
  red[t] = pq; __syncthreads();
  for (int o = 128; o > 0; o >>= 1) { if (t < o) red[t] += red[t + o]; __syncthreads(); }
  float var = red[0] * (1.f / EE) - mu * mu;
  float rs = rsqrtf(var + 1e-5f);
  __syncthreads();
  for (int e = t; e < EE; e += 256)
    nn[e] = (av[e] - mu) * rs * lng[e] + lnb[e];
  __syncthreads();
  for (int j = t; j < FF; j += 256) {
    float s = b1[j];
    for (int e = 0; e < EE; ++e) s += nn[e] * W1[(long)e * FF + j];
    mm[j] = gelu_f(s);
  }
  __syncthreads();
  for (int e = t; e < EE; e += 256) {
    float s = b2[e];
    for (int j = 0; j < FF; ++j) s += mm[j] * W2[(long)j * EE + e];
    hfin[b * EE + e] = s + hf[r * EE + e];
  }
}

// ---------------------------------------------------------------- head (reads hfin[8][512])
__global__ __launch_bounds__(256) void head_kernel(const float* __restrict__ hfin,
                                                   const float* __restrict__ Wh1,
                                                   const float* __restrict__ bh1,
                                                   const float* __restrict__ Wh2,
                                                   const float* __restrict__ bh2,
                                                   float* __restrict__ out) {
  int t = threadIdx.x;
  __shared__ float red[256];
  for (int b = 0; b < BB; ++b) {
    const float* pb = hfin + (long)b * EE;
    float a = bh1[t];
    for (int e = 0; e < EE; ++e) a += pb[e] * Wh1[(long)e * HH + t];
    a = fmaxf(a, 0.f);
    for (int c = 0; c < 2; ++c) {
      red[t] = a * Wh2[t * 2 + c];
      __syncthreads();
      for (int o = 128; o > 0; o >>= 1) { if (t < o) red[t] += red[t + o]; __syncthreads(); }
      if (t == 0) out[b * 2 + c] = red[0] + bh2[c];
      __syncthreads();
    }
  }
}

// ---------------------------------------------------------------- launch
extern "C" void kernel_launch(void* const* d_in, const int* in_sizes, int n_in,
                              void* d_out, int out_size, void* d_ws, size_t ws_size,
                              hipStream_t stream) {
  (void)in_sizes; (void)n_in; (void)out_size;
  const int*   x   = (const int*)d_in[0];
  const float* emb = (const float*)d_in[1];
  const float* pos = (const float*)d_in[2];
  const float* Wq  = (const float*)d_in[3];
  const float* Wk  = (const float*)d_in[4];
  const float* Wv  = (const float*)d_in[5];
  const float* Wo  = (const float*)d_in[6];
  const float* lng = (const float*)d_in[7];
  const float* lnb = (const float*)d_in[8];
  const float* W1  = (const float*)d_in[9];
  const float* b1  = (const float*)d_in[10];
  const float* W2  = (const float*)d_in[11];
  const float* b2  = (const float*)d_in[12];
  const float* Wh1 = (const float*)d_in[13];
  const float* bh1 = (const float*)d_in[14];
  const float* Wh2 = (const float*)d_in[15];
  const float* bh2 = (const float*)d_in[16];
  float* out = (float*)d_out;

  char* ws = (char*)d_ws;
  size_t off = 0;
  auto alloc = [&](size_t bytes) {
    char* p = ws + off;
    off = (off + bytes + 255) & ~(size_t)255;
    return p;
  };
  float* hf   = (float*)alloc((size_t)BS * EE * 4);           // fp32 residual
  u16*   hb   = (u16*)  alloc((size_t)BS * EE * 2);           // bf16 residual copy
  u16*   phi  = (u16*)  alloc((size_t)BS * 128 * 2);          // [g_q | g_k]
  u16*   sbuf = (u16*)  alloc((size_t)BS * EE * 2);           // v -> xi -> n
  float* den  = (float*)alloc((size_t)BS * 4);
  float* Gbuf = (float*)alloc((size_t)BS * 4);
  float* kvpart = (float*)alloc((size_t)NKV * BB * EE * PP * 4);
  float* kvf  = (float*)alloc((size_t)BB * EE * PP * 4 + (size_t)BB * EE * 4);
  float* hbar = kvf + (size_t)BB * EE * PP;
  u16*   kvb  = (u16*)  alloc((size_t)BB * EE * PP * 2);
  float* zg   = (float*)alloc((size_t)BB * PP * 4);
  float* vbar = (float*)alloc((size_t)BB * EE * 4);
  float* kbar = (float*)alloc((size_t)BB * EE * 4);
  float* kwo  = (float*)alloc((size_t)BB * EE * 4);
  float* vwo  = (float*)alloc((size_t)BB * EE * 4);
  float* hfin = (float*)alloc((size_t)BB * EE * 4);
  u16* wqkT = (u16*)alloc((size_t)LL * 128 * EE * 2);
  u16* wvT  = (u16*)alloc((size_t)LL * EE * EE * 2);
  u16* woT  = (u16*)alloc((size_t)LL * EE * EE * 2);
  u16* w1T  = (u16*)alloc((size_t)LL * FF * EE * 2);
  u16* w2T  = (u16*)alloc((size_t)LL * EE * FF * 2);

  // FFN region: af (fp32 LN input) + mbf (bf16 FFN mid), row-chunked to fit ws_size
  size_t rem = (ws_size > off) ? ws_size - off : 0;
  int CH;
  if ((size_t)BS * FF * 2 <= rem) CH = 1;                                  // af aliases mbf
  else if (((size_t)BS * EE * 4 + (size_t)BS * FF * 2) / 2 <= rem) CH = 2;
  else if (((size_t)BS * EE * 4 + (size_t)BS * FF * 2) / 4 <= rem) CH = 4;
  else if (((size_t)BS * EE * 4 + (size_t)BS * FF * 2) / 8 <= rem) CH = 8;
  else CH = 16;
  const int MC = BS / CH;
  char* regp = ws + off;
  float* af = (float*)regp;
  u16* mbf = (CH == 1) ? (u16*)regp : (u16*)(regp + (size_t)MC * EE * 4);

  embed_kernel<<<BS, 128, 0, stream>>>(x, emb, pos, hf, hb);
  transpose_kernel<<<dim3(PP/32, EE/32, LL), 256, 0, stream>>>(Wq, wqkT, EE, PP, (long)EE*PP, (long)128*EE, 0);
  transpose_kernel<<<dim3(PP/32, EE/32, LL), 256, 0, stream>>>(Wk, wqkT, EE, PP, (long)EE*PP, (long)128*EE, 64);
  transpose_kernel<<<dim3(EE/32, EE/32, LL), 256, 0, stream>>>(Wv, wvT, EE, EE, (long)EE*EE, (long)EE*EE, 0);
  transpose_kernel<<<dim3(EE/32, EE/32, LL), 256, 0, stream>>>(Wo, woT, EE, EE, (long)EE*EE, (long)EE*EE, 0);
  transpose_kernel<<<dim3(FF/32, EE/32, LL), 256, 0, stream>>>(W1, w1T, EE, FF, (long)EE*FF, (long)FF*EE, 0);
  transpose_kernel<<<dim3(EE/32, FF/32, LL), 256, 0, stream>>>(W2, w2T, FF, EE, (long)FF*EE, (long)EE*FF, 0);

  for (int l = 0; l < LL; ++l) {
    zero_kernel<<<(BB*EE + 255)/256, 256, 0, stream>>>(hbar, BB*EE);
    hbar_kernel<<<dim3(BB, EE/256, 16), 256, 0, stream>>>(hf, hbar);
    smallmm_kernel<<<dim3(EE/256, BB), 256, 0, stream>>>(hbar, Wv + (size_t)l*EE*EE, vbar);
    {  // g = elu([h Wq | h Wk])
      GemmP p{};
      p.A = hb; p.B = wqkT + (size_t)l * 128 * EE;
      p.M = BS; p.N = 128; p.K = EE;
      p.lda = EE; p.ldb = EE; p.ldc = 128; p.Cb = phi;
      gemm_nt<0><<<dim3(1, BS/128, 1), 256, 0, stream>>>(p);
    }
    {  // v = h Wv (bf16)
      GemmP p{};
      p.A = hb; p.B = wvT + (size_t)l * EE * EE;
      p.M = BS; p.N = EE; p.K = EE;
      p.lda = EE; p.ldb = EE; p.ldc = EE; p.Cb = sbuf;
      gemm_nt<1><<<dim3(EE/128, BS/128, 1), 256, 0, stream>>>(p);
    }
    zg_kernel<<<dim3(PP, BB), 256, 0, stream>>>(phi, zg);
    kv_mfma<<<dim3(EE/128, NKV, BB), 256, 0, stream>>>(phi, sbuf, kvpart);
    kvreduce<<<BB*EE*PP/256, 256, 0, stream>>>(kvpart, kvf, kvb);
    kbar_kernel<<<BB*EE/256, 256, 0, stream>>>(kvf, vbar, kbar);
    smallmm_kernel<<<dim3(EE/256, BB), 256, 0, stream>>>(kbar, Wo + (size_t)l*EE*EE, kwo);
    smallmm_kernel<<<dim3(EE/256, BB), 256, 0, stream>>>(vbar, Wo + (size_t)l*EE*EE, vwo);
    den_kernel<<<BS/256, 256, 0, stream>>>(phi, zg, den, Gbuf);
    if (l < LL - 1) {
      {  // xi = g_q . kv  (bf16)
        GemmP p{};
        p.A = phi; p.B = kvb;
        p.M = SS; p.N = EE; p.K = PP;
        p.lda = 128; p.ldb = PP; p.ldc = EE;
        p.sAz = (long)SS * 128; p.sBz = (long)EE * PP; p.sCz = (long)SS * EE;
        p.Cb = sbuf;
        gemm_nt<1><<<dim3(EE/128, SS/128, BB), 256, 0, stream>>>(p);
      }
      for (int ch = 0; ch < CH; ++ch) {
        int R0 = ch * MC;
        {  // a = (kwo + G*vwo + xi Wo)/den  (fp32)
          GemmP p{};
          p.A = sbuf + (size_t)R0 * EE; p.B = woT + (size_t)l * EE * EE;
          p.M = MC; p.N = EE; p.K = EE;
          p.lda = EE; p.ldb = EE; p.ldc = EE; p.rowOff = R0;
          p.Cf = af; p.den = den; p.G = Gbuf; p.kwo = kwo; p.vwo = vwo;
          gemm_nt<2><<<dim3(EE/128, MC/128, 1), 256, 0, stream>>>(p);
        }
        ln_kernel<<<MC/4, 256, 0, stream>>>(af, lng + (size_t)l*EE, lnb + (size_t)l*EE, sbuf + (size_t)R0 * EE);
        {  // m = gelu(n W1 + b1)
          GemmP p{};
          p.A = sbuf + (size_t)R0 * EE; p.B = w1T + (size_t)l * FF * EE;
          p.M = MC; p.N = FF; p.K = EE;
          p.lda = EE; p.ldb = EE; p.ldc = FF; p.Cb = mbf; p.bias = b1 + (size_t)l * FF;
          gemm_nt<4><<<dim3(FF/128, MC/128, 1), 256, 0, stream>>>(p);
        }
        {  // h += m W2 + b2 (fp32 + bf16 copy)
          GemmP p{};
          p.A = mbf; p.B = w2T + (size_t)l * EE * FF;
          p.M = MC; p.N = EE; p.K = FF;
          p.lda = FF; p.ldb = FF; p.ldc = EE;
          p.hf = hf + (size_t)R0 * EE; p.Cb = hb + (size_t)R0 * EE; p.bias = b2 + (size_t)l * EE;
          gemm_nt<5><<<dim3(EE/128, MC/128, 1), 256, 0, stream>>>(p);
        }
      }
    } else {
      lastrow_kernel<<<BB, 256, 0, stream>>>(phi, kvf, kwo, vwo, Gbuf, den, hf,
                                             Wo + (size_t)l*EE*EE, W1 + (size_t)l*EE*FF,
                                             b1 + (size_t)l*FF, W2 + (size_t)l*FF*EE,
                                             b2 + (size_t)l*EE, lng + (size_t)l*EE,
                                             lnb + (size_t)l*EE, hfin);
    }
  }
  head_kernel<<<1, 256, 0, stream>>>(hfin, Wh1, bh1, Wh2, bh2, out);
}

// Round 4
// 2571.887 us; speedup vs baseline: 1.2806x; 1.0791x over previous
//
#include <hip/hip_runtime.h>
#include <stdint.h>

#define BB 8
#define SS 4096
#define EE 512
#define PP 64
#define LL 4
#define FF 2048
#define HH 256
#define BS (BB*SS)
#define NKV 8   // kv split-K factor

typedef unsigned short u16;
typedef __attribute__((ext_vector_type(8))) __bf16 bf16x8;
typedef __attribute__((ext_vector_type(4))) float f32x4;

__device__ __forceinline__ float b2f(u16 u) {
  union { float f; uint32_t u; } v; v.u = ((uint32_t)u) << 16; return v.f;
}
__device__ __forceinline__ u16 f2b(float f) {
  union { float f; uint32_t u; } v; v.f = f;
  uint32_t u = v.u;
  return (u16)((u + 0x7fffu + ((u >> 16) & 1u)) >> 16);
}
__device__ __forceinline__ float gelu_f(float x) {
  const float c = 0.7978845608028654f;
  float t = tanhf(c * (x + 0.044715f * x * x * x));
  return 0.5f * x * (1.0f + t);
}
// async global(16B) -> LDS, linear dest (wave-uniform base + lane*16)
__device__ __forceinline__ void gload16(const void* g, void* l) {
  auto gp = (const __attribute__((address_space(1))) uint32_t*)(uintptr_t)g;
  auto lp = (__attribute__((address_space(3))) uint32_t*)(uintptr_t)l;
  __builtin_amdgcn_global_load_lds(gp, lp, 16, 0, 0);
}

// ---------------------------------------------------------------- zero
__global__ __launch_bounds__(256) void zero_kernel(float* __restrict__ p, int n) {
  int i = blockIdx.x * 256 + threadIdx.x;
  if (i < n) p[i] = 0.f;
}

// ---------------------------------------------------------------- embed (hf fp32 + hb bf16)
__global__ __launch_bounds__(128) void embed_kernel(const int* __restrict__ x,
                                                    const float* __restrict__ emb,
                                                    const float* __restrict__ pos,
                                                    float* __restrict__ hf,
                                                    u16* __restrict__ hb) {
  int tok = blockIdx.x;
  int t = threadIdx.x;
  int s = tok & (SS - 1);
  int id = x[tok];
  int e = t * 4;
  float4 v = *(const float4*)(emb + (long)id * EE + e);
  float4 p = *(const float4*)(pos + (long)s * EE + e);
  v.x += p.x; v.y += p.y; v.z += p.z; v.w += p.w;
  *(float4*)(hf + (long)tok * EE + e) = v;
  ushort4 u;
  u.x = f2b(v.x); u.y = f2b(v.y); u.z = f2b(v.z); u.w = f2b(v.w);
  *(ushort4*)(hb + (long)tok * EE + e) = u;
}

// ---------------------------------------------------------------- weight transpose fp32 -> bf16
__global__ __launch_bounds__(256) void transpose_kernel(const float* __restrict__ src,
                                                        u16* __restrict__ dst,
                                                        int R, int C,
                                                        long srcLS, long dstLS, int colOff) {
  __shared__ float tile[32][33];
  int l = blockIdx.z;
  src += (long)l * srcLS;
  dst += (long)l * dstLS;
  int c0 = blockIdx.x * 32, r0 = blockIdx.y * 32;
  int tx = threadIdx.x & 31, ty = threadIdx.x >> 5;
#pragma unroll
  for (int i = 0; i < 32; i += 8)
    tile[ty + i][tx] = src[(long)(r0 + ty + i) * C + c0 + tx];
  __syncthreads();
#pragma unroll
  for (int i = 0; i < 32; i += 8)
    dst[(long)(colOff + c0 + ty + i) * R + r0 + tx] = f2b(tile[tx][ty + i]);
}

// ---------------------------------------------------------------- generic NT GEMM (C = A * B^T), bf16 in, f32 acc
// A: M x K (lda), B: N x K (ldb), tile 128x128, BK=64, 4 waves.
// Staging: global_load_lds dwordx4, swizzle applied on the GLOBAL source
// address (per-lane), LDS dest linear. Content layout identical to reg-staged
// version, so the compute-side read swizzle is unchanged.
struct GemmP {
  const u16* A; const u16* B;
  int M, N, K, lda, ldb, ldc, rowOff;
  long sAz, sBz, sCz;
  float* Cf; u16* Cb;
  const float* bias;
  const float* den; const float* G;
  const float* kwo; const float* vwo;
  float* hf;
};

template<int EPI>
__global__ __launch_bounds__(256) void gemm_nt(GemmP p) {
  __shared__ u16 As[128 * 64];
  __shared__ u16 Bs[128 * 64];
  const int z = blockIdx.z;
  const u16* Ap = p.A + (long)z * p.sAz;
  const u16* Bp = p.B + (long)z * p.sBz;
  const int m0 = blockIdx.y * 128, n0 = blockIdx.x * 128;
  const int t = threadIdx.x;
  const int l = t & 63, w = t >> 6;
  const int wr = w >> 1, wc = w & 1;
  const int r16 = l & 15, kg = l >> 4;
  const int srow = l >> 3;                    // row within 8-row segment
  const int scw = ((l & 7) ^ srow) * 8;       // pre-swizzled source chunk (elems)

  f32x4 acc[4][4] = {};

  for (int k0 = 0; k0 < p.K; k0 += 64) {
#pragma unroll
    for (int i = 0; i < 4; ++i) {
      int g = w * 4 + i;                      // segment 0..15 (8 rows x 64 cols)
      int row = g * 8 + srow;
      gload16(Ap + (long)(m0 + row) * p.lda + k0 + scw, &As[g * 512]);
      gload16(Bp + (long)(n0 + row) * p.ldb + k0 + scw, &Bs[g * 512]);
    }
    __syncthreads();
#pragma unroll
    for (int ks = 0; ks < 2; ++ks) {
      bf16x8 af[4], bfr[4];
#pragma unroll
      for (int mi = 0; mi < 4; ++mi) {
        int row = wr * 64 + mi * 16 + r16;
        int ch = (ks * 4 + kg) ^ (row & 7);
        af[mi] = *(const bf16x8*)(&As[row * 64 + ch * 8]);
      }
#pragma unroll
      for (int ni = 0; ni < 4; ++ni) {
        int row = wc * 64 + ni * 16 + r16;
        int ch = (ks * 4 + kg) ^ (row & 7);
        bfr[ni] = *(const bf16x8*)(&Bs[row * 64 + ch * 8]);
      }
#pragma unroll
      for (int mi = 0; mi < 4; ++mi)
#pragma unroll
        for (int ni = 0; ni < 4; ++ni)
          acc[mi][ni] = __builtin_amdgcn_mfma_f32_16x16x32_bf16(af[mi], bfr[ni], acc[mi][ni], 0, 0, 0);
    }
    __syncthreads();
  }

#pragma unroll
  for (int mi = 0; mi < 4; ++mi) {
#pragma unroll
    for (int ni = 0; ni < 4; ++ni) {
#pragma unroll
      for (int j = 0; j < 4; ++j) {
        int row = m0 + wr * 64 + mi * 16 + kg * 4 + j;
        int col = n0 + wc * 64 + ni * 16 + r16;
        float v = acc[mi][ni][j];
        long idx = (long)row * p.ldc + col;
        if constexpr (EPI == 0) {            // g = elu(acc)
          (p.Cb + (long)z * p.sCz)[idx] = f2b(v > 0.f ? v : expf(v) - 1.f);
        } else if constexpr (EPI == 1) {     // plain bf16
          (p.Cb + (long)z * p.sCz)[idx] = f2b(v);
        } else if constexpr (EPI == 2) {     // a = (kwo + G*vwo + xi*Wo)/den
          long grow = p.rowOff + row;
          int b = (int)(grow >> 12);
          float a = (p.kwo[(long)b * EE + col] + p.G[grow] * p.vwo[(long)b * EE + col] + v) / p.den[grow];
          p.Cf[idx] = a;
        } else if constexpr (EPI == 4) {     // gelu(acc + bias)
          p.Cb[idx] = f2b(gelu_f(v + p.bias[col]));
        } else {                             // residual
          float r = v + p.bias[col] + p.hf[idx];
          p.hf[idx] = r;
          p.Cb[idx] = f2b(r);
        }
      }
    }
  }
}

// ---------------------------------------------------------------- kv via MFMA, split-K partials
__global__ __launch_bounds__(256) void kv_mfma(const u16* __restrict__ phi,
                                               const u16* __restrict__ v,
                                               float* __restrict__ kvpart) {
  __shared__ u16 phT[64 * 72];    // [p][s] stride 72
  __shared__ u16 vTs[128 * 72];   // [f][s] stride 72
  const int f0 = blockIdx.x * 128;
  const int kidx = blockIdx.y;
  const int b = blockIdx.z;
  const int t = threadIdx.x;
  const int l = t & 63, w = t >> 6;
  const int r16 = l & 15, kg = l >> 4;

  f32x4 acc[4][2] = {};

  for (int kc = 0; kc < (SS / NKV) / 64; ++kc) {
    const long srow = (long)b * SS + kidx * (SS / NKV) + kc * 64;
#pragma unroll
    for (int pass = 0; pass < 2; ++pass) {
      int pp = t & 63;
      int sb = ((t >> 6) << 3) + pass * 32;
      u16 tmp[8];
#pragma unroll
      for (int j = 0; j < 8; ++j)
        tmp[j] = phi[(srow + sb + j) * 128 + 64 + pp];
      uint4 pk;
      pk.x = (uint32_t)tmp[0] | ((uint32_t)tmp[1] << 16);
      pk.y = (uint32_t)tmp[2] | ((uint32_t)tmp[3] << 16);
      pk.z = (uint32_t)tmp[4] | ((uint32_t)tmp[5] << 16);
      pk.w = (uint32_t)tmp[6] | ((uint32_t)tmp[7] << 16);
      *(uint4*)(&phT[pp * 72 + sb]) = pk;
    }
#pragma unroll
    for (int pass = 0; pass < 4; ++pass) {
      int ff = t & 127;
      int sb = ((t >> 7) << 3) + pass * 16;
      u16 tmp[8];
#pragma unroll
      for (int j = 0; j < 8; ++j)
        tmp[j] = v[(srow + sb + j) * EE + f0 + ff];
      uint4 pk;
      pk.x = (uint32_t)tmp[0] | ((uint32_t)tmp[1] << 16);
      pk.y = (uint32_t)tmp[2] | ((uint32_t)tmp[3] << 16);
      pk.z = (uint32_t)tmp[4] | ((uint32_t)tmp[5] << 16);
      pk.w = (uint32_t)tmp[6] | ((uint32_t)tmp[7] << 16);
      *(uint4*)(&vTs[ff * 72 + sb]) = pk;
    }
    __syncthreads();
#pragma unroll
    for (int ks = 0; ks < 2; ++ks) {
      int sloc = ks * 32 + kg * 8;
      bf16x8 af[4], bfr[2];
#pragma unroll
      for (int mi = 0; mi < 4; ++mi)
        af[mi] = *(const bf16x8*)(&phT[(mi * 16 + r16) * 72 + sloc]);
#pragma unroll
      for (int ni = 0; ni < 2; ++ni)
        bfr[ni] = *(const bf16x8*)(&vTs[(w * 32 + ni * 16 + r16) * 72 + sloc]);
#pragma unroll
      for (int mi = 0; mi < 4; ++mi)
#pragma unroll
        for (int ni = 0; ni < 2; ++ni)
          acc[mi][ni] = __builtin_amdgcn_mfma_f32_16x16x32_bf16(af[mi], bfr[ni], acc[mi][ni], 0, 0, 0);
    }
    __syncthreads();
  }

  float* outp = kvpart + ((long)kidx * BB + b) * EE * PP;
#pragma unroll
  for (int mi = 0; mi < 4; ++mi) {
#pragma unroll
    for (int ni = 0; ni < 2; ++ni) {
#pragma unroll
      for (int j = 0; j < 4; ++j) {
        int pidx = mi * 16 + kg * 4 + j;
        int fidx = f0 + w * 32 + ni * 16 + r16;
        outp[(long)fidx * PP + pidx] = acc[mi][ni][j];
      }
    }
  }
}

// ---------------------------------------------------------------- kv reduce -> kvf (f32) + kvb (bf16)
__global__ __launch_bounds__(256) void kvreduce(const float* __restrict__ kvpart,
                                                float* __restrict__ kvf,
                                                u16* __restrict__ kvb) {
  long i = (long)blockIdx.x * 256 + threadIdx.x;
  const long SKV = (long)BB * EE * PP;
  float s = 0.f;
#pragma unroll
  for (int k = 0; k < NKV; ++k) s += kvpart[k * SKV + i];
  kvf[i] = s;
  kvb[i] = f2b(s);
}

// ---------------------------------------------------------------- zg[b][p] = sum_s g_k
__global__ __launch_bounds__(256) void zg_kernel(const u16* __restrict__ phi, float* __restrict__ zg) {
  int p = blockIdx.x, b = blockIdx.y, t = threadIdx.x;
  float a = 0.f;
  for (int s = t; s < SS; s += 256)
    a += b2f(phi[((long)b * SS + s) * 128 + 64 + p]);
  __shared__ float red[256];
  red[t] = a; __syncthreads();
  for (int o = 128; o > 0; o >>= 1) { if (t < o) red[t] += red[t + o]; __syncthreads(); }
  if (t == 0) zg[b * PP + p] = red[0];
}

// ---------------------------------------------------------------- hbar partial sums
__global__ __launch_bounds__(256) void hbar_kernel(const float* __restrict__ hf, float* __restrict__ hb) {
  int f = blockIdx.y * 256 + threadIdx.x;
  int b = blockIdx.x;
  long s0 = blockIdx.z * 256;
  const float* p = hf + ((long)b * SS + s0) * EE + f;
  float a = 0.f;
  for (int s = 0; s < 256; ++s) a += p[(long)s * EE];
  atomicAdd(&hb[b * EE + f], a);
}

// ---------------------------------------------------------------- out[b][j] = sum_f in[b][f] * W[f][j]
__global__ __launch_bounds__(256) void smallmm_kernel(const float* __restrict__ in,
                                                      const float* __restrict__ W,
                                                      float* __restrict__ out) {
  int j = blockIdx.x * 256 + threadIdx.x;
  int b = blockIdx.y;
  const float* ib = in + b * EE;
  float s = 0.f;
  for (int f = 0; f < EE; ++f) s += ib[f] * W[(long)f * EE + j];
  out[b * EE + j] = s;
}

// ---------------------------------------------------------------- kbar = 64*vbar + sum_p w
__global__ __launch_bounds__(256) void kbar_kernel(const float* __restrict__ kvf,
                                                   const float* __restrict__ vbar,
                                                   float* __restrict__ kb) {
  int i = blockIdx.x * 256 + threadIdx.x;
  const float* wp = kvf + (long)i * PP;
  float s = 0.f;
#pragma unroll
  for (int p = 0; p < PP; ++p) s += wp[p];
  kb[i] = 64.f * vbar[i] + s;
}

// ---------------------------------------------------------------- den[s], G[s]
__global__ __launch_bounds__(256) void den_kernel(const u16* __restrict__ phi,
                                                  const float* __restrict__ zg,
                                                  float* __restrict__ den,
                                                  float* __restrict__ G) {
  long row = (long)blockIdx.x * 256 + threadIdx.x;
  int b = (int)(row >> 12);
  const u16* pr = phi + row * 128;
  const float* zb = zg + b * PP;
  float Gs = 0.f, dot = 0.f, Z = 0.f;
#pragma unroll
  for (int c = 0; c < 8; ++c) {
    uint4 q = *(const uint4*)(pr + c * 8);
    u16 uu[8] = {(u16)(q.x & 0xffff), (u16)(q.x >> 16), (u16)(q.y & 0xffff), (u16)(q.y >> 16),
                 (u16)(q.z & 0xffff), (u16)(q.z >> 16), (u16)(q.w & 0xffff), (u16)(q.w >> 16)};
#pragma unroll
    for (int i = 0; i < 8; ++i) {
      float gq = b2f(uu[i]);
      float zz = zb[c * 8 + i];
      Gs += gq; dot += gq * zz; Z += zz;
    }
  }
  den[row] = 64.f * 4096.f + 4096.f * Gs + Z + dot + 1e-6f;
  G[row] = Gs;
}

// ---------------------------------------------------------------- layernorm (wave per row)
__global__ __launch_bounds__(256) void ln_kernel(const float* __restrict__ a,
                                                 const float* __restrict__ g,
                                                 const float* __restrict__ beta,
                                                 u16* __restrict__ out) {
  int w = threadIdx.x >> 6, l = threadIdx.x & 63;
  long row = (long)blockIdx.x * 4 + w;
  int e = l * 8;
  const float* x = a + row * EE + e;
  float4 v0 = *(const float4*)(x);
  float4 v1 = *(const float4*)(x + 4);
  float vals[8] = {v0.x, v0.y, v0.z, v0.w, v1.x, v1.y, v1.z, v1.w};
  float sum = 0.f, sq = 0.f;
#pragma unroll
  for (int j = 0; j < 8; ++j) { sum += vals[j]; sq += vals[j] * vals[j]; }
#pragma unroll
  for (int o = 1; o < 64; o <<= 1) {
    sum += __shfl_xor(sum, o, 64);
    sq  += __shfl_xor(sq,  o, 64);
  }
  float mu = sum * (1.f / EE);
  float var = sq * (1.f / EE) - mu * mu;
  float rs = rsqrtf(var + 1e-5f);
  u16 ov[8];
#pragma unroll
  for (int j = 0; j < 8; ++j)
    ov[j] = f2b((vals[j] - mu) * rs * g[e + j] + beta[e + j]);
  *(ushort4*)(out + row * EE + e) = *(ushort4*)&ov[0];
  *(ushort4*)(out + row * EE + e + 4) = *(ushort4*)&ov[4];
}

// ---------------------------------------------------------------- last-layer tail (s=0 rows), parallel stages
// A) xi[b][f] = g_q(b,0) . kvf[b][f][:]
__global__ __launch_bounds__(256) void last_xi(const u16* __restrict__ phi,
                                               const float* __restrict__ kvf,
                                               float* __restrict__ xi) {
  int f = blockIdx.x * 256 + threadIdx.x;
  int b = blockIdx.y;
  long r = (long)b * SS;
  const float* kp = kvf + ((long)b * EE + f) * PP;
  float s = 0.f;
#pragma unroll
  for (int p = 0; p < PP; ++p) s += b2f(phi[r * 128 + p]) * kp[p];
  xi[b * EE + f] = s;
}
// B) av[b][e] = (kwo + G*vwo + xi.Wo[:,e]) / den
__global__ __launch_bounds__(256) void last_av(const float* __restrict__ xi,
                                               const float* __restrict__ Wo,
                                               const float* __restrict__ kwo,
                                               const float* __restrict__ vwo,
                                               const float* __restrict__ G,
                                               const float* __restrict__ den,
                                               float* __restrict__ av) {
  __shared__ float xis[EE];
  int e = blockIdx.x * 256 + threadIdx.x;
  int b = blockIdx.y;
  xis[threadIdx.x] = xi[b * EE + threadIdx.x];
  xis[threadIdx.x + 256] = xi[b * EE + threadIdx.x + 256];
  __syncthreads();
  float s = 0.f;
  for (int f = 0; f < EE; ++f) s += xis[f] * Wo[(long)f * EE + e];
  long r = (long)b * SS;
  av[b * EE + e] = (kwo[b * EE + e] + G[r] * vwo[b * EE + e] + s) / den[r];
}
// C) layernorm of the 8 rows -> nn (f32)
__global__ __launch_bounds__(256) void last_ln(const float* __restrict__ av,
                                               const float* __restrict__ g,
                                               const float* __restrict__ beta,
                                               float* __restrict__ nn) {
  __shared__ float red[256];
  int b = blockIdx.x, t = threadIdx.x;
  float v0 = av[b * EE + t], v1 = av[b * EE + t + 256];
  red[t] = v0 + v1; __syncthreads();
  for (int o = 128; o > 0; o >>= 1) { if (t < o) red[t] += red[t + o]; __syncthreads(); }
  float mu = red[0] * (1.f / EE);
  __syncthreads();
  red[t] = v0 * v0 + v1 * v1; __syncthreads();
  for (int o = 128; o > 0; o >>= 1) { if (t < o) red[t] += red[t + o]; __syncthreads(); }
  float var = red[0] * (1.f / EE) - mu * mu;
  float rs = rsqrtf(var + 1e-5f);
  nn[b * EE + t] = (v0 - mu) * rs * g[t] + beta[t];
  nn[b * EE + t + 256] = (v1 - mu) * rs * g[t + 256] + beta[t + 256];
}
// D) mm[b][j] = gelu(b1 + nn.W1[:,j])
__global__ __launch_bounds__(256) void last_w1(const float* __restrict__ nn,
                                               const float* __restrict__ W1,
                                               const float* __restrict__ b1,
                                               float* __restrict__ mm) {
  __shared__ float nns[EE];
  int j = blockIdx.x * 256 + threadIdx.x;
  int b = blockIdx.y;
  nns[threadIdx.x] = nn[b * EE + threadIdx.x];
  nns[threadIdx.x + 256] = nn[b * EE + threadIdx.x + 256];
  __syncthreads();
  float s = b1[j];
  for (int e = 0; e < EE; ++e) s += nns[e] * W1[(long)e * FF + j];
  mm[b * FF + j] = gelu_f(s);
}
// E) hfin[b][e] = b2 + mm.W2[:,e] + hf[b,0,e]
__global__ __launch_bounds__(256) void last_w2(const float* __restrict__ mm,
                                               const float* __restrict__ W2,
                                               const float* __restrict__ b2,
                                               const float* __restrict__ hf,
                                               float* __restrict__ hfin) {
  __shared__ float mms[FF];
  int e = blockIdx.x * 256 + threadIdx.x;
  int b = blockIdx.y;
#pragma unroll
  for (int i = 0; i < 8; ++i)
    mms[threadIdx.x + i * 256] = mm[b * FF + threadIdx.x + i * 256];
  __syncthreads();
  float s = b2[e];
  for (int j = 0; j < FF; ++j) s += mms[j] * W2[(long)j * EE + e];
  hfin[b * EE + e] = s + hf[(long)b * SS * EE + e];
}

// ---------------------------------------------------------------- head (reads hfin[8][512])
__global__ __launch_bounds__(256) void head_kernel(const float* __restrict__ hfin,
                                                   const float* __restrict__ Wh1,
                                                   const float* __restrict__ bh1,
                                                   const float* __restrict__ Wh2,
                                                   const float* __restrict__ bh2,
                                                   float* __restrict__ out) {
  int t = threadIdx.x;
  __shared__ float red[256];
  for (int b = 0; b < BB; ++b) {
    const float* pb = hfin + (long)b * EE;
    float a = bh1[t];
    for (int e = 0; e < EE; ++e) a += pb[e] * Wh1[(long)e * HH + t];
    a = fmaxf(a, 0.f);
    for (int c = 0; c < 2; ++c) {
      red[t] = a * Wh2[t * 2 + c];
      __syncthreads();
      for (int o = 128; o > 0; o >>= 1) { if (t < o) red[t] += red[t + o]; __syncthreads(); }
      if (t == 0) out[b * 2 + c] = red[0] + bh2[c];
      __syncthreads();
    }
  }
}

// ---------------------------------------------------------------- launch
extern "C" void kernel_launch(void* const* d_in, const int* in_sizes, int n_in,
                              void* d_out, int out_size, void* d_ws, size_t ws_size,
                              hipStream_t stream) {
  (void)in_sizes; (void)n_in; (void)out_size;
  const int*   x   = (const int*)d_in[0];
  const float* emb = (const float*)d_in[1];
  const float* pos = (const float*)d_in[2];
  const float* Wq  = (const float*)d_in[3];
  const float* Wk  = (const float*)d_in[4];
  const float* Wv  = (const float*)d_in[5];
  const float* Wo  = (const float*)d_in[6];
  const float* lng = (const float*)d_in[7];
  const float* lnb = (const float*)d_in[8];
  const float* W1  = (const float*)d_in[9];
  const float* b1  = (const float*)d_in[10];
  const float* W2  = (const float*)d_in[11];
  const float* b2  = (const float*)d_in[12];
  const float* Wh1 = (const float*)d_in[13];
  const float* bh1 = (const float*)d_in[14];
  const float* Wh2 = (const float*)d_in[15];
  const float* bh2 = (const float*)d_in[16];
  float* out = (float*)d_out;

  char* ws = (char*)d_ws;
  size_t off = 0;
  auto alloc = [&](size_t bytes) {
    char* p = ws + off;
    off = (off + bytes + 255) & ~(size_t)255;
    return p;
  };
  float* hf   = (float*)alloc((size_t)BS * EE * 4);           // fp32 residual
  u16*   hb   = (u16*)  alloc((size_t)BS * EE * 2);           // bf16 residual copy
  u16*   phi  = (u16*)  alloc((size_t)BS * 128 * 2);          // [g_q | g_k]
  u16*   sbuf = (u16*)  alloc((size_t)BS * EE * 2);           // v -> xi -> n
  float* den  = (float*)alloc((size_t)BS * 4);
  float* Gbuf = (float*)alloc((size_t)BS * 4);
  float* kvpart = (float*)alloc((size_t)NKV * BB * EE * PP * 4);
  float* kvf  = (float*)alloc((size_t)BB * EE * PP * 4 + (size_t)BB * EE * 4);
  float* hbar = kvf + (size_t)BB * EE * PP;
  u16*   kvb  = (u16*)  alloc((size_t)BB * EE * PP * 2);
  float* zg   = (float*)alloc((size_t)BB * PP * 4);
  float* vbar = (float*)alloc((size_t)BB * EE * 4);
  float* kbar = (float*)alloc((size_t)BB * EE * 4);
  float* kwo  = (float*)alloc((size_t)BB * EE * 4);
  float* vwo  = (float*)alloc((size_t)BB * EE * 4);
  float* hfin = (float*)alloc((size_t)BB * EE * 4);
  float* xib  = (float*)alloc((size_t)BB * EE * 4);
  float* avb  = (float*)alloc((size_t)BB * EE * 4);
  float* nnb  = (float*)alloc((size_t)BB * EE * 4);
  float* mmb  = (float*)alloc((size_t)BB * FF * 4);
  u16* wqkT = (u16*)alloc((size_t)LL * 128 * EE * 2);
  u16* wvT  = (u16*)alloc((size_t)LL * EE * EE * 2);
  u16* woT  = (u16*)alloc((size_t)LL * EE * EE * 2);
  u16* w1T  = (u16*)alloc((size_t)LL * FF * EE * 2);
  u16* w2T  = (u16*)alloc((size_t)LL * EE * FF * 2);

  // FFN region: af (fp32 LN input) + mbf (bf16 FFN mid), row-chunked to fit ws_size
  size_t rem = (ws_size > off) ? ws_size - off : 0;
  int CH;
  if ((size_t)BS * FF * 2 <= rem) CH = 1;                                  // af aliases mbf
  else if (((size_t)BS * EE * 4 + (size_t)BS * FF * 2) / 2 <= rem) CH = 2;
  else if (((size_t)BS * EE * 4 + (size_t)BS * FF * 2) / 4 <= rem) CH = 4;
  else if (((size_t)BS * EE * 4 + (size_t)BS * FF * 2) / 8 <= rem) CH = 8;
  else CH = 16;
  const int MC = BS / CH;
  char* regp = ws + off;
  float* af = (float*)regp;
  u16* mbf = (CH == 1) ? (u16*)regp : (u16*)(regp + (size_t)MC * EE * 4);

  embed_kernel<<<BS, 128, 0, stream>>>(x, emb, pos, hf, hb);
  transpose_kernel<<<dim3(PP/32, EE/32, LL), 256, 0, stream>>>(Wq, wqkT, EE, PP, (long)EE*PP, (long)128*EE, 0);
  transpose_kernel<<<dim3(PP/32, EE/32, LL), 256, 0, stream>>>(Wk, wqkT, EE, PP, (long)EE*PP, (long)128*EE, 64);
  transpose_kernel<<<dim3(EE/32, EE/32, LL), 256, 0, stream>>>(Wv, wvT, EE, EE, (long)EE*EE, (long)EE*EE, 0);
  transpose_kernel<<<dim3(EE/32, EE/32, LL), 256, 0, stream>>>(Wo, woT, EE, EE, (long)EE*EE, (long)EE*EE, 0);
  transpose_kernel<<<dim3(FF/32, EE/32, LL), 256, 0, stream>>>(W1, w1T, EE, FF, (long)EE*FF, (long)FF*EE, 0);
  transpose_kernel<<<dim3(EE/32, FF/32, LL), 256, 0, stream>>>(W2, w2T, FF, EE, (long)FF*EE, (long)EE*FF, 0);

  for (int l = 0; l < LL; ++l) {
    zero_kernel<<<(BB*EE + 255)/256, 256, 0, stream>>>(hbar, BB*EE);
    hbar_kernel<<<dim3(BB, EE/256, 16), 256, 0, stream>>>(hf, hbar);
    smallmm_kernel<<<dim3(EE/256, BB), 256, 0, stream>>>(hbar, Wv + (size_t)l*EE*EE, vbar);
    {  // g = elu([h Wq | h Wk])
      GemmP p{};
      p.A = hb; p.B = wqkT + (size_t)l * 128 * EE;
      p.M = BS; p.N = 128; p.K = EE;
      p.lda = EE; p.ldb = EE; p.ldc = 128; p.Cb = phi;
      gemm_nt<0><<<dim3(1, BS/128, 1), 256, 0, stream>>>(p);
    }
    {  // v = h Wv (bf16)
      GemmP p{};
      p.A = hb; p.B = wvT + (size_t)l * EE * EE;
      p.M = BS; p.N = EE; p.K = EE;
      p.lda = EE; p.ldb = EE; p.ldc = EE; p.Cb = sbuf;
      gemm_nt<1><<<dim3(EE/128, BS/128, 1), 256, 0, stream>>>(p);
    }
    zg_kernel<<<dim3(PP, BB), 256, 0, stream>>>(phi, zg);
    kv_mfma<<<dim3(EE/128, NKV, BB), 256, 0, stream>>>(phi, sbuf, kvpart);
    kvreduce<<<BB*EE*PP/256, 256, 0, stream>>>(kvpart, kvf, kvb);
    kbar_kernel<<<BB*EE/256, 256, 0, stream>>>(kvf, vbar, kbar);
    smallmm_kernel<<<dim3(EE/256, BB), 256, 0, stream>>>(kbar, Wo + (size_t)l*EE*EE, kwo);
    smallmm_kernel<<<dim3(EE/256, BB), 256, 0, stream>>>(vbar, Wo + (size_t)l*EE*EE, vwo);
    den_kernel<<<BS/256, 256, 0, stream>>>(phi, zg, den, Gbuf);
    if (l < LL - 1) {
      {  // xi = g_q . kv  (bf16)
        GemmP p{};
        p.A = phi; p.B = kvb;
        p.M = SS; p.N = EE; p.K = PP;
        p.lda = 128; p.ldb = PP; p.ldc = EE;
        p.sAz = (long)SS * 128; p.sBz = (long)EE * PP; p.sCz = (long)SS * EE;
        p.Cb = sbuf;
        gemm_nt<1><<<dim3(EE/128, SS/128, BB), 256, 0, stream>>>(p);
      }
      for (int ch = 0; ch < CH; ++ch) {
        int R0 = ch * MC;
        {  // a = (kwo + G*vwo + xi Wo)/den  (fp32)
          GemmP p{};
          p.A = sbuf + (size_t)R0 * EE; p.B = woT + (size_t)l * EE * EE;
          p.M = MC; p.N = EE; p.K = EE;
          p.lda = EE; p.ldb = EE; p.ldc = EE; p.rowOff = R0;
          p.Cf = af; p.den = den; p.G = Gbuf; p.kwo = kwo; p.vwo = vwo;
          gemm_nt<2><<<dim3(EE/128, MC/128, 1), 256, 0, stream>>>(p);
        }
        ln_kernel<<<MC/4, 256, 0, stream>>>(af, lng + (size_t)l*EE, lnb + (size_t)l*EE, sbuf + (size_t)R0 * EE);
        {  // m = gelu(n W1 + b1)
          GemmP p{};
          p.A = sbuf + (size_t)R0 * EE; p.B = w1T + (size_t)l * FF * EE;
          p.M = MC; p.N = FF; p.K = EE;
          p.lda = EE; p.ldb = EE; p.ldc = FF; p.Cb = mbf; p.bias = b1 + (size_t)l * FF;
          gemm_nt<4><<<dim3(FF/128, MC/128, 1), 256, 0, stream>>>(p);
        }
        {  // h += m W2 + b2 (fp32 + bf16 copy)
          GemmP p{};
          p.A = mbf; p.B = w2T + (size_t)l * EE * FF;
          p.M = MC; p.N = EE; p.K = FF;
          p.lda = FF; p.ldb = FF; p.ldc = EE;
          p.hf = hf + (size_t)R0 * EE; p.Cb = hb + (size_t)R0 * EE; p.bias = b2 + (size_t)l * EE;
          gemm_nt<5><<<dim3(EE/128, MC/128, 1), 256, 0, stream>>>(p);
        }
      }
    } else {
      last_xi<<<dim3(EE/256, BB), 256, 0, stream>>>(phi, kvf, xib);
      last_av<<<dim3(EE/256, BB), 256, 0, stream>>>(xib, Wo + (size_t)l*EE*EE, kwo, vwo, Gbuf, den, avb);
      last_ln<<<BB, 256, 0, stream>>>(avb, lng + (size_t)l*EE, lnb + (size_t)l*EE, nnb);
      last_w1<<<dim3(FF/256, BB), 256, 0, stream>>>(nnb, W1 + (size_t)l*EE*FF, b1 + (size_t)l*FF, mmb);
      last_w2<<<dim3(EE/256, BB), 256, 0, stream>>>(mmb, W2 + (size_t)l*FF*EE, b2 + (size_t)l*EE, hf, hfin);
    }
  }
  head_kernel<<<1, 256, 0, stream>>>(hfin, Wh1, bh1, Wh2, bh2, out);
}

// Round 5
// 2390.465 us; speedup vs baseline: 1.3778x; 1.0759x over previous
//
#include <hip/hip_runtime.h>
#include <stdint.h>

#define BB 8
#define SS 4096
#define EE 512
#define PP 64
#define LL 4
#define FF 2048
#define HH 256
#define BS (BB*SS)
#define NKV 16   // kv split-K factor

typedef unsigned short u16;
typedef __attribute__((ext_vector_type(8))) __bf16 bf16x8;
typedef __attribute__((ext_vector_type(4))) float f32x4;

__device__ __forceinline__ float b2f(u16 u) {
  union { float f; uint32_t u; } v; v.u = ((uint32_t)u) << 16; return v.f;
}
__device__ __forceinline__ u16 f2b(float f) {
  union { float f; uint32_t u; } v; v.f = f;
  uint32_t u = v.u;
  return (u16)((u + 0x7fffu + ((u >> 16) & 1u)) >> 16);
}
__device__ __forceinline__ float gelu_f(float x) {
  const float c = 0.7978845608028654f;
  float t = tanhf(c * (x + 0.044715f * x * x * x));
  return 0.5f * x * (1.0f + t);
}
// async global(16B) -> LDS, linear dest (wave-uniform base + lane*16)
__device__ __forceinline__ void gload16(const void* g, void* l) {
  auto gp = (const __attribute__((address_space(1))) uint32_t*)(uintptr_t)g;
  auto lp = (__attribute__((address_space(3))) uint32_t*)(uintptr_t)l;
  __builtin_amdgcn_global_load_lds(gp, lp, 16, 0, 0);
}

// ---------------------------------------------------------------- zero
__global__ __launch_bounds__(256) void zero_kernel(float* __restrict__ p, int n) {
  int i = blockIdx.x * 256 + threadIdx.x;
  if (i < n) p[i] = 0.f;
}

// ---------------------------------------------------------------- embed (hf fp32 + hb bf16)
__global__ __launch_bounds__(128) void embed_kernel(const int* __restrict__ x,
                                                    const float* __restrict__ emb,
                                                    const float* __restrict__ pos,
                                                    float* __restrict__ hf,
                                                    u16* __restrict__ hb) {
  int tok = blockIdx.x;
  int t = threadIdx.x;
  int s = tok & (SS - 1);
  int id = x[tok];
  int e = t * 4;
  float4 v = *(const float4*)(emb + (long)id * EE + e);
  float4 p = *(const float4*)(pos + (long)s * EE + e);
  v.x += p.x; v.y += p.y; v.z += p.z; v.w += p.w;
  *(float4*)(hf + (long)tok * EE + e) = v;
  ushort4 u;
  u.x = f2b(v.x); u.y = f2b(v.y); u.z = f2b(v.z); u.w = f2b(v.w);
  *(ushort4*)(hb + (long)tok * EE + e) = u;
}

// ---------------------------------------------------------------- weight transpose fp32 -> bf16
__global__ __launch_bounds__(256) void transpose_kernel(const float* __restrict__ src,
                                                        u16* __restrict__ dst,
                                                        int R, int C,
                                                        long srcLS, long dstLS, int colOff) {
  __shared__ float tile[32][33];
  int l = blockIdx.z;
  src += (long)l * srcLS;
  dst += (long)l * dstLS;
  int c0 = blockIdx.x * 32, r0 = blockIdx.y * 32;
  int tx = threadIdx.x & 31, ty = threadIdx.x >> 5;
#pragma unroll
  for (int i = 0; i < 32; i += 8)
    tile[ty + i][tx] = src[(long)(r0 + ty + i) * C + c0 + tx];
  __syncthreads();
#pragma unroll
  for (int i = 0; i < 32; i += 8)
    dst[(long)(colOff + c0 + ty + i) * R + r0 + tx] = f2b(tile[tx][ty + i]);
}

// ---------------------------------------------------------------- generic NT GEMM (C = A * B^T), bf16 in, f32 acc
// tile 128x128, BK=64, 4 waves, global_load_lds staging w/ source-side swizzle
// EPI: 0 = elu(acc)->phi + phiT(k-half) ; 1 = bf16 ; 2 = (kwo+G*vwo+acc)/den->f32
//      4 = gelu(acc+bias)->bf16 ; 5 = residual ; 6 = bf16 transposed only (vT)
struct GemmP {
  const u16* A; const u16* B;
  int M, N, K, lda, ldb, ldc, rowOff;
  long sAz, sBz, sCz;
  float* Cf; u16* Cb; u16* CbT;
  const float* bias;
  const float* den; const float* G;
  const float* kwo; const float* vwo;
  float* hf;
};

template<int EPI>
__global__ __launch_bounds__(256) void gemm_nt(GemmP p) {
  __shared__ u16 As[128 * 64];
  __shared__ u16 Bs[128 * 64];
  const int z = blockIdx.z;
  const u16* Ap = p.A + (long)z * p.sAz;
  const u16* Bp = p.B + (long)z * p.sBz;
  const int m0 = blockIdx.y * 128, n0 = blockIdx.x * 128;
  const int t = threadIdx.x;
  const int l = t & 63, w = t >> 6;
  const int wr = w >> 1, wc = w & 1;
  const int r16 = l & 15, kg = l >> 4;
  const int srow = l >> 3;
  const int scw = ((l & 7) ^ srow) * 8;

  f32x4 acc[4][4] = {};

  for (int k0 = 0; k0 < p.K; k0 += 64) {
#pragma unroll
    for (int i = 0; i < 4; ++i) {
      int g = w * 4 + i;
      int row = g * 8 + srow;
      gload16(Ap + (long)(m0 + row) * p.lda + k0 + scw, &As[g * 512]);
      gload16(Bp + (long)(n0 + row) * p.ldb + k0 + scw, &Bs[g * 512]);
    }
    __syncthreads();
#pragma unroll
    for (int ks = 0; ks < 2; ++ks) {
      bf16x8 af[4], bfr[4];
#pragma unroll
      for (int mi = 0; mi < 4; ++mi) {
        int row = wr * 64 + mi * 16 + r16;
        int ch = (ks * 4 + kg) ^ (row & 7);
        af[mi] = *(const bf16x8*)(&As[row * 64 + ch * 8]);
      }
#pragma unroll
      for (int ni = 0; ni < 4; ++ni) {
        int row = wc * 64 + ni * 16 + r16;
        int ch = (ks * 4 + kg) ^ (row & 7);
        bfr[ni] = *(const bf16x8*)(&Bs[row * 64 + ch * 8]);
      }
#pragma unroll
      for (int mi = 0; mi < 4; ++mi)
#pragma unroll
        for (int ni = 0; ni < 4; ++ni)
          acc[mi][ni] = __builtin_amdgcn_mfma_f32_16x16x32_bf16(af[mi], bfr[ni], acc[mi][ni], 0, 0, 0);
    }
    __syncthreads();
  }

#pragma unroll
  for (int mi = 0; mi < 4; ++mi) {
#pragma unroll
    for (int ni = 0; ni < 4; ++ni) {
      const int rowB = m0 + wr * 64 + mi * 16 + kg * 4;   // s base (j=0..3)
      const int col  = n0 + wc * 64 + ni * 16 + r16;
      if constexpr (EPI == 0) {            // phi = elu(acc), + phiT for k-half
        u16 e4[4];
#pragma unroll
        for (int j = 0; j < 4; ++j) {
          float v = acc[mi][ni][j];
          e4[j] = f2b(v > 0.f ? v : expf(v) - 1.f);
          p.Cb[(long)(rowB + j) * p.ldc + col] = e4[j];
        }
        if (col >= 64) {
          uint2 pk;
          pk.x = (uint32_t)e4[0] | ((uint32_t)e4[1] << 16);
          pk.y = (uint32_t)e4[2] | ((uint32_t)e4[3] << 16);
          long b = rowB >> 12;
          *(uint2*)(&p.CbT[((long)(b * 64 + (col - 64))) * SS + (rowB & (SS - 1))]) = pk;
        }
      } else if constexpr (EPI == 6) {     // vT only
        u16 e4[4];
#pragma unroll
        for (int j = 0; j < 4; ++j) e4[j] = f2b(acc[mi][ni][j]);
        uint2 pk;
        pk.x = (uint32_t)e4[0] | ((uint32_t)e4[1] << 16);
        pk.y = (uint32_t)e4[2] | ((uint32_t)e4[3] << 16);
        long b = rowB >> 12;
        *(uint2*)(&p.CbT[((long)(b * EE + col)) * SS + (rowB & (SS - 1))]) = pk;
      } else {
#pragma unroll
        for (int j = 0; j < 4; ++j) {
          int row = rowB + j;
          float v = acc[mi][ni][j];
          long idx = (long)row * p.ldc + col;
          if constexpr (EPI == 1) {
            (p.Cb + (long)z * p.sCz)[idx] = f2b(v);
          } else if constexpr (EPI == 2) {
            long grow = p.rowOff + row;
            int b = (int)(grow >> 12);
            float a = (p.kwo[(long)b * EE + col] + p.G[grow] * p.vwo[(long)b * EE + col] + v) / p.den[grow];
            p.Cf[idx] = a;
          } else if constexpr (EPI == 4) {
            p.Cb[idx] = f2b(gelu_f(v + p.bias[col]));
          } else {                         // 5: residual
            float r = v + p.bias[col] + p.hf[idx];
            p.hf[idx] = r;
            p.Cb[idx] = f2b(r);
          }
        }
      }
    }
  }
}

// ---------------------------------------------------------------- kv NT GEMM: kv[p][f] = sum_s phiT[p][s] * vT[f][s]
// grid (EE/128, NKV, BB), 256 thr; M=64, N=128, K-chunk 256 (BK=64)
__global__ __launch_bounds__(256) void kv_nt(const u16* __restrict__ phiT,
                                             const u16* __restrict__ vT,
                                             float* __restrict__ kvpart) {
  __shared__ u16 As[64 * 64];
  __shared__ u16 Bs[128 * 64];
  const int f0 = blockIdx.x * 128;
  const int kidx = blockIdx.y;
  const int b = blockIdx.z;
  const u16* Ap = phiT + (long)b * 64 * SS;
  const u16* Bp = vT + (long)b * EE * SS;
  const int t = threadIdx.x;
  const int l = t & 63, w = t >> 6;
  const int r16 = l & 15, kg = l >> 4;
  const int srow = l >> 3;
  const int scw = ((l & 7) ^ srow) * 8;

  f32x4 acc[4][2] = {};
  const int kbase = kidx * (SS / NKV);
  for (int k0 = kbase; k0 < kbase + SS / NKV; k0 += 64) {
#pragma unroll
    for (int i = 0; i < 2; ++i) {
      int g = w * 2 + i;
      gload16(Ap + (long)(g * 8 + srow) * SS + k0 + scw, &As[g * 512]);
    }
#pragma unroll
    for (int i = 0; i < 4; ++i) {
      int g = w * 4 + i;
      gload16(Bp + (long)(f0 + g * 8 + srow) * SS + k0 + scw, &Bs[g * 512]);
    }
    __syncthreads();
#pragma unroll
    for (int ks = 0; ks < 2; ++ks) {
      bf16x8 af[4], bfr[2];
#pragma unroll
      for (int mi = 0; mi < 4; ++mi) {
        int row = mi * 16 + r16;
        int ch = (ks * 4 + kg) ^ (row & 7);
        af[mi] = *(const bf16x8*)(&As[row * 64 + ch * 8]);
      }
#pragma unroll
      for (int ni = 0; ni < 2; ++ni) {
        int row = w * 32 + ni * 16 + r16;
        int ch = (ks * 4 + kg) ^ (row & 7);
        bfr[ni] = *(const bf16x8*)(&Bs[row * 64 + ch * 8]);
      }
#pragma unroll
      for (int mi = 0; mi < 4; ++mi)
#pragma unroll
        for (int ni = 0; ni < 2; ++ni)
          acc[mi][ni] = __builtin_amdgcn_mfma_f32_16x16x32_bf16(af[mi], bfr[ni], acc[mi][ni], 0, 0, 0);
    }
    __syncthreads();
  }

  float* outp = kvpart + ((long)kidx * BB + b) * EE * PP;
#pragma unroll
  for (int mi = 0; mi < 4; ++mi)
#pragma unroll
    for (int ni = 0; ni < 2; ++ni)
#pragma unroll
      for (int j = 0; j < 4; ++j)
        outp[(long)(f0 + w * 32 + ni * 16 + r16) * PP + mi * 16 + kg * 4 + j] = acc[mi][ni][j];
}

// ---------------------------------------------------------------- kv reduce -> kvf (f32) + kvb (bf16)
__global__ __launch_bounds__(256) void kvreduce(const float* __restrict__ kvpart,
                                                float* __restrict__ kvf,
                                                u16* __restrict__ kvb) {
  long i = (long)blockIdx.x * 256 + threadIdx.x;
  const long SKV = (long)BB * EE * PP;
  float s = 0.f;
#pragma unroll
  for (int k = 0; k < NKV; ++k) s += kvpart[k * SKV + i];
  kvf[i] = s;
  kvb[i] = f2b(s);
}

// ---------------------------------------------------------------- zg[b][p] = sum_s phiT row (linear)
__global__ __launch_bounds__(256) void zg_kernel(const u16* __restrict__ phiT, float* __restrict__ zg) {
  int p = blockIdx.x, b = blockIdx.y, t = threadIdx.x;
  const u16* row = phiT + ((long)b * 64 + p) * SS + t * 16;
  float a = 0.f;
#pragma unroll
  for (int c = 0; c < 2; ++c) {
    uint4 q = *(const uint4*)(row + c * 8);
    uint32_t qq[4] = {q.x, q.y, q.z, q.w};
#pragma unroll
    for (int i = 0; i < 4; ++i) {
      a += b2f((u16)(qq[i] & 0xffff)) + b2f((u16)(qq[i] >> 16));
    }
  }
  __shared__ float red[256];
  red[t] = a; __syncthreads();
  for (int o = 128; o > 0; o >>= 1) { if (t < o) red[t] += red[t + o]; __syncthreads(); }
  if (t == 0) zg[b * PP + p] = red[0];
}

// ---------------------------------------------------------------- hbar partial sums
__global__ __launch_bounds__(256) void hbar_kernel(const float* __restrict__ hf, float* __restrict__ hb) {
  int f = blockIdx.y * 256 + threadIdx.x;
  int b = blockIdx.x;
  long s0 = blockIdx.z * 256;
  const float* p = hf + ((long)b * SS + s0) * EE + f;
  float a = 0.f;
  for (int s = 0; s < 256; ++s) a += p[(long)s * EE];
  atomicAdd(&hb[b * EE + f], a);
}

// ---------------------------------------------------------------- out[b][j] = sum_f in[b][f] * W[f][j]
__global__ __launch_bounds__(256) void smallmm_kernel(const float* __restrict__ in,
                                                      const float* __restrict__ W,
                                                      float* __restrict__ out) {
  int j = blockIdx.x * 256 + threadIdx.x;
  int b = blockIdx.y;
  const float* ib = in + b * EE;
  float s = 0.f;
  for (int f = 0; f < EE; ++f) s += ib[f] * W[(long)f * EE + j];
  out[b * EE + j] = s;
}

// ---------------------------------------------------------------- kbar = 64*vbar + sum_p w
__global__ __launch_bounds__(256) void kbar_kernel(const float* __restrict__ kvf,
                                                   const float* __restrict__ vbar,
                                                   float* __restrict__ kb) {
  int i = blockIdx.x * 256 + threadIdx.x;
  const float* wp = kvf + (long)i * PP;
  float s = 0.f;
#pragma unroll
  for (int p = 0; p < PP; ++p) s += wp[p];
  kb[i] = 64.f * vbar[i] + s;
}

// ---------------------------------------------------------------- den[s], G[s]
__global__ __launch_bounds__(256) void den_kernel(const u16* __restrict__ phi,
                                                  const float* __restrict__ zg,
                                                  float* __restrict__ den,
                                                  float* __restrict__ G) {
  long row = (long)blockIdx.x * 256 + threadIdx.x;
  int b = (int)(row >> 12);
  const u16* pr = phi + row * 128;
  const float* zb = zg + b * PP;
  float Gs = 0.f, dot = 0.f, Z = 0.f;
#pragma unroll
  for (int c = 0; c < 8; ++c) {
    uint4 q = *(const uint4*)(pr + c * 8);
    u16 uu[8] = {(u16)(q.x & 0xffff), (u16)(q.x >> 16), (u16)(q.y & 0xffff), (u16)(q.y >> 16),
                 (u16)(q.z & 0xffff), (u16)(q.z >> 16), (u16)(q.w & 0xffff), (u16)(q.w >> 16)};
#pragma unroll
    for (int i = 0; i < 8; ++i) {
      float gq = b2f(uu[i]);
      float zz = zb[c * 8 + i];
      Gs += gq; dot += gq * zz; Z += zz;
    }
  }
  den[row] = 64.f * 4096.f + 4096.f * Gs + Z + dot + 1e-6f;
  G[row] = Gs;
}

// ---------------------------------------------------------------- layernorm (wave per row)
__global__ __launch_bounds__(256) void ln_kernel(const float* __restrict__ a,
                                                 const float* __restrict__ g,
                                                 const float* __restrict__ beta,
                                                 u16* __restrict__ out) {
  int w = threadIdx.x >> 6, l = threadIdx.x & 63;
  long row = (long)blockIdx.x * 4 + w;
  int e = l * 8;
  const float* x = a + row * EE + e;
  float4 v0 = *(const float4*)(x);
  float4 v1 = *(const float4*)(x + 4);
  float vals[8] = {v0.x, v0.y, v0.z, v0.w, v1.x, v1.y, v1.z, v1.w};
  float sum = 0.f, sq = 0.f;
#pragma unroll
  for (int j = 0; j < 8; ++j) { sum += vals[j]; sq += vals[j] * vals[j]; }
#pragma unroll
  for (int o = 1; o < 64; o <<= 1) {
    sum += __shfl_xor(sum, o, 64);
    sq  += __shfl_xor(sq,  o, 64);
  }
  float mu = sum * (1.f / EE);
  float var = sq * (1.f / EE) - mu * mu;
  float rs = rsqrtf(var + 1e-5f);
  u16 ov[8];
#pragma unroll
  for (int j = 0; j < 8; ++j)
    ov[j] = f2b((vals[j] - mu) * rs * g[e + j] + beta[e + j]);
  *(ushort4*)(out + row * EE + e) = *(ushort4*)&ov[0];
  *(ushort4*)(out + row * EE + e + 4) = *(ushort4*)&ov[4];
}

// ---------------------------------------------------------------- last-layer tail (s=0 rows, fp32 exact)
// A) xi[b][f]
__global__ __launch_bounds__(256) void last_xi(const u16* __restrict__ phi,
                                               const float* __restrict__ kvf,
                                               float* __restrict__ xi) {
  int f = blockIdx.x * 256 + threadIdx.x;
  int b = blockIdx.y;
  long r = (long)b * SS;
  const float* kp = kvf + ((long)b * EE + f) * PP;
  float s = 0.f;
#pragma unroll
  for (int p = 0; p < PP; ++p) s += b2f(phi[r * 128 + p]) * kp[p];
  xi[b * EE + f] = s;
}
// B) avp[kc][b][e] = partial xi.Wo over f-chunk
__global__ __launch_bounds__(256) void last_av(const float* __restrict__ xi,
                                               const float* __restrict__ Wo,
                                               float* __restrict__ avp) {
  __shared__ float xis[128];
  int e = blockIdx.x * 256 + threadIdx.x;
  int b = blockIdx.y;
  int f0 = blockIdx.z * 128;
  if (threadIdx.x < 128) xis[threadIdx.x] = xi[b * EE + f0 + threadIdx.x];
  __syncthreads();
  float s = 0.f;
  for (int f = 0; f < 128; ++f) s += xis[f] * Wo[(long)(f0 + f) * EE + e];
  avp[((long)blockIdx.z * BB + b) * EE + e] = s;
}
// C) combine + layernorm -> nn (f32)
__global__ __launch_bounds__(256) void last_ln(const float* __restrict__ avp,
                                               const float* __restrict__ kwo,
                                               const float* __restrict__ vwo,
                                               const float* __restrict__ G,
                                               const float* __restrict__ den,
                                               const float* __restrict__ g,
                                               const float* __restrict__ beta,
                                               float* __restrict__ nn) {
  __shared__ float red[256];
  int b = blockIdx.x, t = threadIdx.x;
  long r = (long)b * SS;
  float Gr = G[r], dr = den[r];
  float v0 = kwo[b * EE + t] + Gr * vwo[b * EE + t];
  float v1 = kwo[b * EE + t + 256] + Gr * vwo[b * EE + t + 256];
#pragma unroll
  for (int c = 0; c < 4; ++c) {
    v0 += avp[((long)c * BB + b) * EE + t];
    v1 += avp[((long)c * BB + b) * EE + t + 256];
  }
  v0 /= dr; v1 /= dr;
  red[t] = v0 + v1; __syncthreads();
  for (int o = 128; o > 0; o >>= 1) { if (t < o) red[t] += red[t + o]; __syncthreads(); }
  float mu = red[0] * (1.f / EE);
  __syncthreads();
  red[t] = v0 * v0 + v1 * v1; __syncthreads();
  for (int o = 128; o > 0; o >>= 1) { if (t < o) red[t] += red[t + o]; __syncthreads(); }
  float var = red[0] * (1.f / EE) - mu * mu;
  float rs = rsqrtf(var + 1e-5f);
  nn[b * EE + t] = (v0 - mu) * rs * g[t] + beta[t];
  nn[b * EE + t + 256] = (v1 - mu) * rs * g[t + 256] + beta[t + 256];
}
// D1) mmp[ec][b][j] = partial nn.W1
__global__ __launch_bounds__(256) void last_w1(const float* __restrict__ nn,
                                               const float* __restrict__ W1,
                                               float* __restrict__ mmp) {
  __shared__ float nns[256];
  int j = blockIdx.x * 256 + threadIdx.x;
  int b = blockIdx.y;
  int e0 = blockIdx.z * 256;
  nns[threadIdx.x] = nn[b * EE + e0 + threadIdx.x];
  __syncthreads();
  float s = 0.f;
  for (int e = 0; e < 256; ++e) s += nns[e] * W1[(long)(e0 + e) * FF + j];
  mmp[((long)blockIdx.z * BB + b) * FF + j] = s;
}
// D2) mm = gelu(b1 + sum partials)
__global__ __launch_bounds__(256) void last_w1c(const float* __restrict__ mmp,
                                                const float* __restrict__ b1,
                                                float* __restrict__ mm) {
  int j = blockIdx.x * 256 + threadIdx.x;
  int b = blockIdx.y;
  float s = b1[j] + mmp[(long)b * FF + j] + mmp[((long)BB + b) * FF + j];
  mm[b * FF + j] = gelu_f(s);
}
// E1) hfp[jc][b][e] = partial mm.W2
__global__ __launch_bounds__(256) void last_w2(const float* __restrict__ mm,
                                               const float* __restrict__ W2,
                                               float* __restrict__ hfp) {
  __shared__ float mms[256];
  int e = blockIdx.x * 256 + threadIdx.x;
  int b = blockIdx.y;
  int j0 = blockIdx.z * 256;
  mms[threadIdx.x] = mm[b * FF + j0 + threadIdx.x];
  __syncthreads();
  float s = 0.f;
  for (int j = 0; j < 256; ++j) s += mms[j] * W2[(long)(j0 + j) * EE + e];
  hfp[((long)blockIdx.z * BB + b) * EE + e] = s;
}
// E2) hfin = b2 + sum partials + residual
__global__ __launch_bounds__(256) void last_w2c(const float* __restrict__ hfp,
                                                const float* __restrict__ b2,
                                                const float* __restrict__ hf,
                                                float* __restrict__ hfin) {
  int e = blockIdx.x * 256 + threadIdx.x;
  int b = blockIdx.y;
  float s = b2[e];
#pragma unroll
  for (int jc = 0; jc < 8; ++jc) s += hfp[((long)jc * BB + b) * EE + e];
  hfin[b * EE + e] = s + hf[(long)b * SS * EE + e];
}

// ---------------------------------------------------------------- head, 2-stage
__global__ __launch_bounds__(256) void head1(const float* __restrict__ hfin,
                                             const float* __restrict__ Wh1,
                                             float* __restrict__ hp) {
  __shared__ float hs[128];
  int j = threadIdx.x;          // 0..255 (HH)
  int b = blockIdx.y;
  int e0 = blockIdx.x * 128;
  if (j < 128) hs[j] = hfin[b * EE + e0 + j];
  __syncthreads();
  float a = 0.f;
  for (int e = 0; e < 128; ++e) a += hs[e] * Wh1[(long)(e0 + e) * HH + j];
  hp[((long)blockIdx.x * BB + b) * HH + j] = a;
}
__global__ __launch_bounds__(256) void head2(const float* __restrict__ hp,
                                             const float* __restrict__ bh1,
                                             const float* __restrict__ Wh2,
                                             const float* __restrict__ bh2,
                                             float* __restrict__ out) {
  __shared__ float red[256];
  int t = threadIdx.x;
  for (int b = 0; b < BB; ++b) {
    float a = bh1[t];
#pragma unroll
    for (int c = 0; c < 4; ++c) a += hp[((long)c * BB + b) * HH + t];
    a = fmaxf(a, 0.f);
    for (int c = 0; c < 2; ++c) {
      red[t] = a * Wh2[t * 2 + c];
      __syncthreads();
      for (int o = 128; o > 0; o >>= 1) { if (t < o) red[t] += red[t + o]; __syncthreads(); }
      if (t == 0) out[b * 2 + c] = red[0] + bh2[c];
      __syncthreads();
    }
  }
}

// ---------------------------------------------------------------- launch
extern "C" void kernel_launch(void* const* d_in, const int* in_sizes, int n_in,
                              void* d_out, int out_size, void* d_ws, size_t ws_size,
                              hipStream_t stream) {
  (void)in_sizes; (void)n_in; (void)out_size;
  const int*   x   = (const int*)d_in[0];
  const float* emb = (const float*)d_in[1];
  const float* pos = (const float*)d_in[2];
  const float* Wq  = (const float*)d_in[3];
  const float* Wk  = (const float*)d_in[4];
  const float* Wv  = (const float*)d_in[5];
  const float* Wo  = (const float*)d_in[6];
  const float* lng = (const float*)d_in[7];
  const float* lnb = (const float*)d_in[8];
  const float* W1  = (const float*)d_in[9];
  const float* b1  = (const float*)d_in[10];
  const float* W2  = (const float*)d_in[11];
  const float* b2  = (const float*)d_in[12];
  const float* Wh1 = (const float*)d_in[13];
  const float* bh1 = (const float*)d_in[14];
  const float* Wh2 = (const float*)d_in[15];
  const float* bh2 = (const float*)d_in[16];
  float* out = (float*)d_out;

  char* ws = (char*)d_ws;
  size_t off = 0;
  auto alloc = [&](size_t bytes) {
    char* p = ws + off;
    off = (off + bytes + 255) & ~(size_t)255;
    return p;
  };
  float* hf   = (float*)alloc((size_t)BS * EE * 4);           // fp32 residual
  u16*   hb   = (u16*)  alloc((size_t)BS * EE * 2);           // bf16 residual copy
  u16*   phi  = (u16*)  alloc((size_t)BS * 128 * 2);          // [g_q | g_k] row-major
  u16*   phiT = (u16*)  alloc((size_t)BB * 64 * SS * 2);      // g_k transposed [b][p][s]
  u16*   sbuf = (u16*)  alloc((size_t)BS * EE * 2);           // xi -> n (bf16)
  float* den  = (float*)alloc((size_t)BS * 4);
  float* Gbuf = (float*)alloc((size_t)BS * 4);
  float* kvpart = (float*)alloc((size_t)NKV * BB * EE * PP * 4);
  float* kvf  = (float*)alloc((size_t)BB * EE * PP * 4 + (size_t)BB * EE * 4);
  float* hbar = kvf + (size_t)BB * EE * PP;
  u16*   kvb  = (u16*)  alloc((size_t)BB * EE * PP * 2);
  float* zg   = (float*)alloc((size_t)BB * PP * 4);
  float* vbar = (float*)alloc((size_t)BB * EE * 4);
  float* kbar = (float*)alloc((size_t)BB * EE * 4);
  float* kwo  = (float*)alloc((size_t)BB * EE * 4);
  float* vwo  = (float*)alloc((size_t)BB * EE * 4);
  float* hfin = (float*)alloc((size_t)BB * EE * 4);
  float* xib  = (float*)alloc((size_t)BB * EE * 4);
  float* nnb  = (float*)alloc((size_t)BB * EE * 4);
  float* avp  = (float*)alloc((size_t)4 * BB * EE * 4);
  float* mmp  = (float*)alloc((size_t)2 * BB * FF * 4);
  float* mmb  = (float*)alloc((size_t)BB * FF * 4);
  float* hfp  = (float*)alloc((size_t)8 * BB * EE * 4);
  float* hpb  = (float*)alloc((size_t)4 * BB * HH * 4);
  u16* wqkT = (u16*)alloc((size_t)LL * 128 * EE * 2);
  u16* wvT  = (u16*)alloc((size_t)LL * EE * EE * 2);
  u16* woT  = (u16*)alloc((size_t)LL * EE * EE * 2);
  u16* w1T  = (u16*)alloc((size_t)LL * FF * EE * 2);
  u16* w2T  = (u16*)alloc((size_t)LL * EE * FF * 2);

  // region: vT (32MB, used pre-FFN) aliases af/mbf (used post-xi). Row-chunk FFN to fit.
  size_t rem = (ws_size > off) ? ws_size - off : 0;
  const size_t vtBytes = (size_t)BB * EE * SS * 2;            // 32 MB
  int CH;
  if ((size_t)BS * FF * 2 <= rem) CH = 1;
  else if (((size_t)BS * EE * 4 + (size_t)BS * FF * 2) / 2 <= rem) CH = 2;
  else if (((size_t)BS * EE * 4 + (size_t)BS * FF * 2) / 4 <= rem) CH = 4;
  else CH = 8;   // region >= vtBytes still required below
  (void)vtBytes;
  const int MC = BS / CH;
  char* regp = ws + off;
  u16* vT = (u16*)regp;
  float* af = (float*)regp;
  u16* mbf = (CH == 1) ? (u16*)regp : (u16*)(regp + (size_t)MC * EE * 4);

  embed_kernel<<<BS, 128, 0, stream>>>(x, emb, pos, hf, hb);
  transpose_kernel<<<dim3(PP/32, EE/32, LL), 256, 0, stream>>>(Wq, wqkT, EE, PP, (long)EE*PP, (long)128*EE, 0);
  transpose_kernel<<<dim3(PP/32, EE/32, LL), 256, 0, stream>>>(Wk, wqkT, EE, PP, (long)EE*PP, (long)128*EE, 64);
  transpose_kernel<<<dim3(EE/32, EE/32, LL), 256, 0, stream>>>(Wv, wvT, EE, EE, (long)EE*EE, (long)EE*EE, 0);
  transpose_kernel<<<dim3(EE/32, EE/32, LL), 256, 0, stream>>>(Wo, woT, EE, EE, (long)EE*EE, (long)EE*EE, 0);
  transpose_kernel<<<dim3(FF/32, EE/32, LL), 256, 0, stream>>>(W1, w1T, EE, FF, (long)EE*FF, (long)FF*EE, 0);
  transpose_kernel<<<dim3(EE/32, FF/32, LL), 256, 0, stream>>>(W2, w2T, FF, EE, (long)FF*EE, (long)EE*FF, 0);

  for (int l = 0; l < LL; ++l) {
    zero_kernel<<<(BB*EE + 255)/256, 256, 0, stream>>>(hbar, BB*EE);
    hbar_kernel<<<dim3(BB, EE/256, 16), 256, 0, stream>>>(hf, hbar);
    smallmm_kernel<<<dim3(EE/256, BB), 256, 0, stream>>>(hbar, Wv + (size_t)l*EE*EE, vbar);
    {  // g = elu([h Wq | h Wk]) -> phi + phiT
      GemmP p{};
      p.A = hb; p.B = wqkT + (size_t)l * 128 * EE;
      p.M = BS; p.N = 128; p.K = EE;
      p.lda = EE; p.ldb = EE; p.ldc = 128; p.Cb = phi; p.CbT = phiT;
      gemm_nt<0><<<dim3(1, BS/128, 1), 256, 0, stream>>>(p);
    }
    {  // vT = (h Wv)^T (bf16, transposed only)
      GemmP p{};
      p.A = hb; p.B = wvT + (size_t)l * EE * EE;
      p.M = BS; p.N = EE; p.K = EE;
      p.lda = EE; p.ldb = EE; p.ldc = EE; p.CbT = vT;
      gemm_nt<6><<<dim3(EE/128, BS/128, 1), 256, 0, stream>>>(p);
    }
    zg_kernel<<<dim3(PP, BB), 256, 0, stream>>>(phiT, zg);
    kv_nt<<<dim3(EE/128, NKV, BB), 256, 0, stream>>>(phiT, vT, kvpart);
    kvreduce<<<BB*EE*PP/256, 256, 0, stream>>>(kvpart, kvf, kvb);
    kbar_kernel<<<BB*EE/256, 256, 0, stream>>>(kvf, vbar, kbar);
    smallmm_kernel<<<dim3(EE/256, BB), 256, 0, stream>>>(kbar, Wo + (size_t)l*EE*EE, kwo);
    smallmm_kernel<<<dim3(EE/256, BB), 256, 0, stream>>>(vbar, Wo + (size_t)l*EE*EE, vwo);
    den_kernel<<<BS/256, 256, 0, stream>>>(phi, zg, den, Gbuf);
    if (l < LL - 1) {
      {  // xi = g_q . kv  (bf16)
        GemmP p{};
        p.A = phi; p.B = kvb;
        p.M = SS; p.N = EE; p.K = PP;
        p.lda = 128; p.ldb = PP; p.ldc = EE;
        p.sAz = (long)SS * 128; p.sBz = (long)EE * PP; p.sCz = (long)SS * EE;
        p.Cb = sbuf;
        gemm_nt<1><<<dim3(EE/128, SS/128, BB), 256, 0, stream>>>(p);
      }
      for (int ch = 0; ch < CH; ++ch) {
        int R0 = ch * MC;
        {  // a = (kwo + G*vwo + xi Wo)/den  (fp32)
          GemmP p{};
          p.A = sbuf + (size_t)R0 * EE; p.B = woT + (size_t)l * EE * EE;
          p.M = MC; p.N = EE; p.K = EE;
          p.lda = EE; p.ldb = EE; p.ldc = EE; p.rowOff = R0;
          p.Cf = af; p.den = den; p.G = Gbuf; p.kwo = kwo; p.vwo = vwo;
          gemm_nt<2><<<dim3(EE/128, MC/128, 1), 256, 0, stream>>>(p);
        }
        ln_kernel<<<MC/4, 256, 0, stream>>>(af, lng + (size_t)l*EE, lnb + (size_t)l*EE, sbuf + (size_t)R0 * EE);
        {  // m = gelu(n W1 + b1)
          GemmP p{};
          p.A = sbuf + (size_t)R0 * EE; p.B = w1T + (size_t)l * FF * EE;
          p.M = MC; p.N = FF; p.K = EE;
          p.lda = EE; p.ldb = EE; p.ldc = FF; p.Cb = mbf; p.bias = b1 + (size_t)l * FF;
          gemm_nt<4><<<dim3(FF/128, MC/128, 1), 256, 0, stream>>>(p);
        }
        {  // h += m W2 + b2 (fp32 + bf16 copy)
          GemmP p{};
          p.A = mbf; p.B = w2T + (size_t)l * EE * FF;
          p.M = MC; p.N = EE; p.K = FF;
          p.lda = FF; p.ldb = FF; p.ldc = EE;
          p.hf = hf + (size_t)R0 * EE; p.Cb = hb + (size_t)R0 * EE; p.bias = b2 + (size_t)l * EE;
          gemm_nt<5><<<dim3(EE/128, MC/128, 1), 256, 0, stream>>>(p);
        }
      }
    } else {
      last_xi<<<dim3(EE/256, BB), 256, 0, stream>>>(phi, kvf, xib);
      last_av<<<dim3(EE/256, BB, 4), 256, 0, stream>>>(xib, Wo + (size_t)l*EE*EE, avp);
      last_ln<<<BB, 256, 0, stream>>>(avp, kwo, vwo, Gbuf, den,
                                      lng + (size_t)l*EE, lnb + (size_t)l*EE, nnb);
      last_w1<<<dim3(FF/256, BB, 2), 256, 0, stream>>>(nnb, W1 + (size_t)l*EE*FF, mmp);
      last_w1c<<<dim3(FF/256, BB), 256, 0, stream>>>(mmp, b1 + (size_t)l*FF, mmb);
      last_w2<<<dim3(EE/256, BB, 8), 256, 0, stream>>>(mmb, W2 + (size_t)l*FF*EE, hfp);
      last_w2c<<<dim3(EE/256, BB), 256, 0, stream>>>(hfp, b2 + (size_t)l*EE, hf, hfin);
    }
  }
  head1<<<dim3(4, BB), 256, 0, stream>>>(hfin, Wh1, hpb);
  head2<<<1, 256, 0, stream>>>(hpb, bh1, Wh2, bh2, out);
}